// Round 8
// baseline (1665.481 us; speedup 1.0000x reference)
//
#include <hip/hip_runtime.h>
#include <hip/hip_bf16.h>
#include <cstdint>
#include <cstddef>
#include <math.h>

// GraphResNet forward, round 8.
// Coarse gather rebuilt PAIR-PARALLEL with atomicAdd (R7's target-parallel walk was
// 0.9 waves/SIMD, VGPR=4, fully latency-bound at 300us). k_ygemm now skips spline
// bins with zero pairs (pseudo-coords cluster centrally -> ~75% of bins empty).
// Fine convs: edge-parallel msg kernels, coalesced [k][cin][cout] weights, L5 bf16.

namespace {

constexpr int NB    = 2;
constexpr int NPER  = 4096;
constexpr int NN    = NB * NPER;        // 8192 nodes
constexpr int NE    = NN * 6;           // 49152 edges
constexpr int KT    = 512;              // 8^3 spline table
constexpr int NV5   = 225;
constexpr int NCV   = NB * NV5;         // 450 coarse voxels
constexpr int NSLOT = NB * 16;
constexpr int NUM_OUT = 11;
constexpr int GE    = (NE + 255) / 256;
constexpr int GP    = (NE * 8 + 255) / 256;

__device__ __forceinline__ void atomicMaxF(float* a, float v) {
  if (v >= 0.f) atomicMax((int*)a, __float_as_int(v));
  else          atomicMin((unsigned int*)a, __float_as_uint(v));
}

__device__ __forceinline__ float bfu(unsigned int u) { return __uint_as_float(u << 16); }

__device__ __forceinline__ void spline8(float p0, float p1, float p2, float* bas, int* idx) {
  float l0 = floorf(p0), l1 = floorf(p1), l2 = floorf(p2);
  float f0 = p0 - l0, f1 = p1 - l1, f2 = p2 - l2;
  int i0 = (int)l0, i1 = (int)l1, i2 = (int)l2;
#pragma unroll
  for (int s = 0; s < 8; ++s) {
    int b0 = s & 1, b1 = (s >> 1) & 1, b2 = (s >> 2) & 1;
    float w = (b0 ? f0 : 1.f - f0) * (b1 ? f1 : 1.f - f1) * (b2 ? f2 : 1.f - f2);
    int j0 = min(max(i0 + b0, 0), 7);
    int j1 = min(max(i1 + b1, 0), 7);
    int j2 = min(max(i2 + b2, 0), 7);
    bas[s] = w;
    idx[s] = j0 + (j1 << 3) + (j2 << 6);
  }
}

__global__ void k_fill(float* p, float v, int n) {
  int i = blockIdx.x * blockDim.x + threadIdx.x;
  if (i < n) p[i] = v;
}

__global__ void k_spline(const float* __restrict__ ea, float* __restrict__ basis,
                         int* __restrict__ widx) {
  int e = blockIdx.x * blockDim.x + threadIdx.x;
  if (e >= NE) return;
  float bas[8]; int idx[8];
  spline8(ea[e*3+0]*7.f, ea[e*3+1]*7.f, ea[e*3+2]*7.f, bas, idx);
#pragma unroll
  for (int s = 0; s < 8; ++s) { basis[e*8+s] = bas[s]; widx[e*8+s] = idx[s]; }
}

__global__ void k_hist(const int* __restrict__ t, int* deg, int n) {
  int i = blockIdx.x * blockDim.x + threadIdx.x;
  if (i < n) atomicAdd(&deg[t[i]], 1);
}

__global__ void k_scan(const int* __restrict__ deg, int* __restrict__ row,
                       int* __restrict__ cursor, int n) {
  __shared__ int part[256];
  int tid = threadIdx.x;
  int chunk = (n + 255) / 256;
  int s0 = tid * chunk, s1 = min(s0 + chunk, n);
  int s = 0;
  for (int i = s0; i < s1; ++i) s += deg[i];
  part[tid] = s;
  __syncthreads();
  for (int off = 1; off < 256; off <<= 1) {
    int v = (tid >= off) ? part[tid - off] : 0;
    __syncthreads();
    part[tid] += v;
    __syncthreads();
  }
  int run = (tid == 0) ? 0 : part[tid - 1];
  for (int i = s0; i < s1; ++i) { row[i] = run; cursor[i] = run; run += deg[i]; }
  if (tid == 255) row[n] = run;
}

__global__ void k_scatter(const int* __restrict__ t, int* cursor, int* __restrict__ perm,
                          const int* nptr, int nconst) {
  int n = nptr ? *nptr : nconst;
  int i = blockIdx.x * blockDim.x + threadIdx.x;
  if (i >= n) return;
  int pos = atomicAdd(&cursor[t[i]], 1);
  perm[pos] = i;
}

// ---- edge-parallel fine-conv messages (coalesced W reads) ----

__global__ __launch_bounds__(256)
void k_msg1(const float* __restrict__ x, const int* __restrict__ src,
            const float* __restrict__ basis, const int* __restrict__ widx,
            const float* __restrict__ W1, float* __restrict__ msg) {
  int e = blockIdx.x * 16 + (threadIdx.x >> 4);
  int f = threadIdx.x & 15;
  if (e >= NE) return;
  float xv = x[src[e]];
  float acc = 0.f;
#pragma unroll
  for (int b = 0; b < 8; ++b) {
    float bb = basis[e*8+b];
    int k = widx[e*8+b];
    acc += bb * W1[(size_t)k * 16 + f];
  }
  msg[(size_t)e * 16 + f] = acc * xv;
}

template<int CIN>
__global__ __launch_bounds__(256)
void k_msg_mid(const float* __restrict__ x, const int* __restrict__ src,
               const float* __restrict__ basis, const int* __restrict__ widx,
               const float* __restrict__ Wk, float* __restrict__ msg) {
  int e = blockIdx.x * 8 + (threadIdx.x >> 5);
  int f = threadIdx.x & 31;
  if (e >= NE) return;
  int s = src[e];
  float xv = (f < CIN) ? x[(size_t)s * CIN + f] : 0.f;
  float bs[8]; int ks[8];
#pragma unroll
  for (int b = 0; b < 8; ++b) { bs[b] = basis[e*8+b]; ks[b] = widx[e*8+b]; }
  float acc = 0.f;
#pragma unroll
  for (int b = 0; b < 8; ++b) {
    const float* Wp = Wk + (size_t)ks[b] * (CIN * 32) + f;
    float m = 0.f;
#pragma unroll
    for (int c = 0; c < CIN; ++c) m += __shfl(xv, c, 32) * Wp[c * 32];
    acc += bs[b] * m;
  }
  msg[(size_t)e * 32 + f] = acc;
}

__global__ __launch_bounds__(256)
void k_msg5(const float* __restrict__ x, const int* __restrict__ src,
            const float* __restrict__ basis, const int* __restrict__ widx,
            const unsigned short* __restrict__ W5h, float* __restrict__ msg) {
  __shared__ float xs[2][32];
  int sub = threadIdx.x >> 7;
  int f = threadIdx.x & 127;
  int e = blockIdx.x * 2 + sub;
  int s = src[e];
  if (f < 32) xs[sub][f] = x[(size_t)s * 32 + f];
  __syncthreads();
  float xv[32];
#pragma unroll
  for (int c = 0; c < 32; ++c) xv[c] = xs[sub][c];
  float bs[8]; int ks[8];
#pragma unroll
  for (int b = 0; b < 8; ++b) { bs[b] = basis[e*8+b]; ks[b] = widx[e*8+b]; }
  float acc = 0.f;
#pragma unroll
  for (int b = 0; b < 8; ++b) {
    const unsigned short* Wp = W5h + (size_t)ks[b] * 4096 + f;
    float m = 0.f;
#pragma unroll
    for (int c = 0; c < 32; ++c) m += xv[c] * bfu((unsigned int)Wp[c * 128]);
    acc += bs[b] * m;
  }
  msg[(size_t)e * 128 + f] = acc;
}

template<int C>
__global__ __launch_bounds__(256)
void k_agg(const float* __restrict__ msg, const int* __restrict__ perm,
           const int* __restrict__ row, float* __restrict__ hout, int n) {
  constexpr int TPB = 256 / C;
  int t = blockIdx.x * TPB + threadIdx.x / C;
  int f = threadIdx.x % C;
  if (t >= n) return;
  int r0 = row[t], r1 = row[t + 1];
  float acc = 0.f;
  for (int i = r0; i < r1; ++i) acc += msg[(size_t)perm[i] * C + f];
  float h = acc / (float)max(r1 - r0, 1);
  hout[(size_t)t * C + f] = h > 0.f ? h : expm1f(h);
}

__global__ void k_wt5cvt(const float* __restrict__ W, unsigned short* __restrict__ Wh) {
  int i = blockIdx.x * 256 + threadIdx.x;
  if (i >= KT * 32 * 128) return;
  __hip_bfloat16 h = __float2bfloat16(W[i]);
  union { __hip_bfloat16 b; unsigned short u; } cv; cv.b = h;
  Wh[i] = cv.u;
}

// BN stats / norm
template<int C>
__global__ void k_bn_stats(const float* __restrict__ h, const float* __restrict__ maskf,
                           double* __restrict__ stats, int n) {
  constexpr int RPB = 256 / C;
  int f = threadIdx.x % C;
  int r = threadIdx.x / C;
  float s = 0.f, ss = 0.f;
  for (int i = blockIdx.x * RPB + r; i < n; i += gridDim.x * RPB) {
    float v = h[(size_t)i * C + f];
    if (maskf) v *= maskf[i];
    s += v; ss += v * v;
  }
  __shared__ float ls[256], lss[256];
  ls[threadIdx.x] = s; lss[threadIdx.x] = ss;
  __syncthreads();
  if (r == 0) {
#pragma unroll
    for (int j = 1; j < RPB; ++j) { s += ls[j * C + f]; ss += lss[j * C + f]; }
    atomicAdd(&stats[f], (double)s);
    atomicAdd(&stats[C + f], (double)ss);
  }
}

__global__ void k_bn_norm(float* __restrict__ h, const double* __restrict__ stats,
                          const float* cntp, int defn, const float* __restrict__ g,
                          const float* __restrict__ b, const float* __restrict__ sc,
                          int total, int Cmask) {
  int i = blockIdx.x * blockDim.x + threadIdx.x;
  if (i >= total) return;
  int f = i & Cmask;
  double cnt = cntp ? (double)fmaxf(*cntp, 1.f) : (double)defn;
  double m = stats[f] / cnt;
  double v = stats[(Cmask + 1) + f] / cnt - m * m;
  float inv = rsqrtf((float)v + 1e-5f);
  float val = (h[i] - (float)m) * inv * g[f] + b[f];
  if (sc) val += sc[i];
  h[i] = val;
}

// pooling / coarse graph construction
__global__ void k_pool5(const float* __restrict__ h, const float* __restrict__ pos,
                        const int* __restrict__ batch, int* __restrict__ cl,
                        float* cnt, float* posps, float* xp) {
  int i = blockIdx.x * blockDim.x + threadIdx.x;
  if (i >= NN * 128) return;
  int node = i >> 7, f = i & 127;
  float px = pos[node*3+0], py = pos[node*3+1];
  int vx = min(max((int)floorf(px / 16.f), 0), 14);
  int vy = min(max((int)floorf(py / 12.f), 0), 14);
  int c = batch[node] * NV5 + vy * 15 + vx;
  if (f == 0) { cl[node] = c; atomicAdd(&cnt[c], 1.f); }
  if (f < 3) atomicAdd(&posps[c*3+f], pos[node*3+f]);
  atomicMaxF(&xp[(size_t)c * 128 + f], h[(size_t)node * 128 + f]);
}

__global__ void k_pool5_fin(float* xp, const float* __restrict__ cnt,
                            const float* __restrict__ posps, float* posp,
                            float* validf, float* nvalid) {
  int i = blockIdx.x * blockDim.x + threadIdx.x;
  if (i >= NCV * 128) return;
  int c = i >> 7, f = i & 127;
  bool val = cnt[c] > 0.f;
  if (f == 0) { validf[c] = val ? 1.f : 0.f; if (val) atomicAdd(nvalid, 1.f); }
  if (f < 3) posp[c*3+f] = posps[c*3+f] / fmaxf(cnt[c], 1.f);
  xp[i] = val ? xp[i] : 0.f;
}

__global__ void k_claim(const int* __restrict__ src, const int* __restrict__ tgt,
                        const int* __restrict__ cl, int* marker, int* ce_s, int* ce_d,
                        int* nedge, int* deg2, unsigned int* amax,
                        const float* __restrict__ posp) {
  int e = blockIdx.x * blockDim.x + threadIdx.x;
  if (e >= NE) return;
  int cs = cl[src[e]], ct = cl[tgt[e]];
  int key = cs * NCV + ct;
  if (atomicCAS(&marker[key], 0, 1) == 0 && cs != ct) {
    int id = atomicAdd(nedge, 1);
    ce_s[id] = cs; ce_d[id] = ct;
    atomicAdd(&deg2[ct], 1);
#pragma unroll
    for (int d = 0; d < 3; ++d) {
      float a = fabsf(posp[cs*3+d] - posp[ct*3+d]);
      atomicMax(amax, __float_as_uint(a));
    }
  }
}

__global__ void k_spline2(const int* __restrict__ ce_s, const int* __restrict__ ce_d,
                          const float* __restrict__ posp, const unsigned int* amaxp,
                          const int* nedgep, float* __restrict__ basis2,
                          int* __restrict__ widx2) {
  int i = blockIdx.x * blockDim.x + threadIdx.x;
  if (i >= *nedgep) return;
  float am = __uint_as_float(*amaxp);
  float den = 2.f * am + 1e-12f;
  int cs = ce_s[i], ct = ce_d[i];
  float p[3];
#pragma unroll
  for (int d = 0; d < 3; ++d) {
    float cart = posp[cs*3+d] - posp[ct*3+d];
    float ps = cart / den + 0.5f;
    ps = fminf(fmaxf(ps, 0.f), 1.f);
    p[d] = ps * 7.f;
  }
  float bas[8]; int idx[8];
  spline8(p[0], p[1], p[2], bas, idx);
#pragma unroll
  for (int s = 0; s < 8; ++s) { basis2[i*8+s] = bas[s]; widx2[i*8+s] = idx[s]; }
}

// histogram of pair spline-indices (to skip empty k bins in ygemm)
__global__ void k_phist(const int* __restrict__ widx2, const int* nedgep, int* pk_deg) {
  int i = blockIdx.x * blockDim.x + threadIdx.x;
  if (i >= 8 * (*nedgep)) return;
  atomicAdd(&pk_deg[widx2[i]], 1);
}

// batched Y[kk] = X(450x128) @ W[k0+kk](128x128); skips bins with no pairs.
__global__ __launch_bounds__(256)
void k_ygemm(const float* __restrict__ X, const float* __restrict__ Wk,
             float* __restrict__ Y, const int* __restrict__ pk_row, int k0) {
  int tile = blockIdx.x & 7;
  int kk = blockIdx.x >> 3;
  int k = k0 + kk;
  if (pk_row[k + 1] == pk_row[k]) return;   // no pairs use this bin
  int n0 = tile * 64;
  __shared__ float Xs[64][32];
  __shared__ float Ws[32][128];
  int tid = threadIdx.x;
  int tx = tid & 31;
  int ty = tid >> 5;
  float acc[8][4];
#pragma unroll
  for (int i = 0; i < 8; ++i)
#pragma unroll
    for (int j = 0; j < 4; ++j) acc[i][j] = 0.f;
  for (int c0 = 0; c0 < 128; c0 += 32) {
    for (int idx = tid; idx < 64 * 32; idx += 256) {
      int n = idx >> 5, c = idx & 31;
      int gn = n0 + n;
      Xs[n][c] = (gn < NCV) ? X[(size_t)gn * 128 + c0 + c] : 0.f;
    }
    for (int idx = tid; idx < 32 * 128; idx += 256) {
      int c = idx >> 7, f = idx & 127;
      Ws[c][f] = Wk[((size_t)k * 128 + c0 + c) * 128 + f];
    }
    __syncthreads();
#pragma unroll 8
    for (int c = 0; c < 32; ++c) {
      float4 wv = *(const float4*)&Ws[c][tx * 4];
#pragma unroll
      for (int i = 0; i < 8; ++i) {
        float xv = Xs[ty * 8 + i][c];
        acc[i][0] += xv * wv.x; acc[i][1] += xv * wv.y;
        acc[i][2] += xv * wv.z; acc[i][3] += xv * wv.w;
      }
    }
    __syncthreads();
  }
#pragma unroll
  for (int i = 0; i < 8; ++i) {
    int gn = n0 + ty * 8 + i;
    if (gn < NCV) {
      float4 v = make_float4(acc[i][0], acc[i][1], acc[i][2], acc[i][3]);
      *(float4*)&Y[((size_t)kk * NCV + gn) * 128 + tx * 4] = v;
    }
  }
}

// pair-parallel gather: one wave per (edge,corner); float2 Y-row read + atomicAdd.
__global__ __launch_bounds__(256)
void k_gather2a(const float* __restrict__ Y, const int* __restrict__ ce_s,
                const int* __restrict__ ce_d, const float* __restrict__ basis2,
                const int* __restrict__ widx2, const int* nedgep,
                float* __restrict__ num2, int k0, int k1) {
  int npair = 8 * (*nedgep);
  int wid = (blockIdx.x * 256 + threadIdx.x) >> 6;
  int lane = threadIdx.x & 63;
  int nw = (gridDim.x * 256) >> 6;
  for (int pidx = wid; pidx < npair; pidx += nw) {
    int k = widx2[pidx];
    if (k < k0 || k >= k1) continue;
    int e = pidx >> 3;
    float bb = basis2[pidx];
    int s = ce_s[e], t = ce_d[e];
    float2 v = ((const float2*)(Y + ((size_t)(k - k0) * NCV + s) * 128))[lane];
    float* dst = num2 + (size_t)t * 128 + lane * 2;
    atomicAdd(dst, bb * v.x);
    atomicAdd(dst + 1, bb * v.y);
  }
}

__global__ void k_elu_div(const float* __restrict__ num, const int* __restrict__ deg,
                          float* __restrict__ h, int total) {
  int i = blockIdx.x * blockDim.x + threadIdx.x;
  if (i >= total) return;
  int r = i >> 7;
  float v = num[i] / (float)max(deg[r], 1);
  h[i] = v > 0.f ? v : expm1f(v);
}

__global__ void k_pool7(const float* __restrict__ h2, const float* __restrict__ posp,
                        const float* __restrict__ validf, float* x7, float* cnt7) {
  int i = blockIdx.x * blockDim.x + threadIdx.x;
  if (i >= NCV * 128) return;
  int c = i >> 7, f = i & 127;
  bool val = validf[c] > 0.f;
  float hv = val ? h2[i] : -1e30f;
  float px = posp[c*3+0], py = posp[c*3+1];
  int vx = min(max((int)floorf(px / 60.f), 0), 3);
  int vy = min(max((int)floorf(py / 45.f), 0), 3);
  int s = (c / NV5) * 16 + vy * 4 + vx;
  atomicMaxF(&x7[(size_t)s * 128 + f], hv);
  if (f == 0) atomicAdd(&cnt7[s], validf[c]);
}

__global__ void k_x7fin(float* x7, const float* __restrict__ cnt7) {
  int i = blockIdx.x * blockDim.x + threadIdx.x;
  if (i >= NSLOT * 128) return;
  x7[i] = (cnt7[i >> 7] > 0.f) ? x7[i] : 0.f;
}

__global__ void k_fc(const float* __restrict__ x7, const float* __restrict__ Wfc,
                     float* __restrict__ out) {
  int bid = blockIdx.x;
  int s = bid / NUM_OUT, o = bid % NUM_OUT;
  float p = 0.f;
  for (int j = threadIdx.x; j < 16 * 128; j += 256)
    p += x7[(size_t)s * 2048 + j] * Wfc[(size_t)o * 2048 + j];
  __shared__ float red[256];
  red[threadIdx.x] = p;
  __syncthreads();
  for (int st = 128; st > 0; st >>= 1) {
    if (threadIdx.x < st) red[threadIdx.x] += red[threadIdx.x + st];
    __syncthreads();
  }
  if (threadIdx.x == 0) out[s * NUM_OUT + o] = red[0];
}

} // namespace

extern "C" void kernel_launch(void* const* d_in, const int* in_sizes, int n_in,
                              void* d_out, int out_size, void* d_ws, size_t ws_size,
                              hipStream_t stream) {
  (void)in_sizes; (void)n_in; (void)out_size;
  const float* x_in  = (const float*)d_in[0];
  const float* pos   = (const float*)d_in[1];
  const float* eattr = (const float*)d_in[2];
  const int*   eidx  = (const int*)d_in[3];
  const int*   batch = (const int*)d_in[4];
  const float *Wl[8], *gl[8], *bl[8];
  for (int l = 1; l <= 7; ++l) {
    Wl[l] = (const float*)d_in[5 + (l - 1) * 3 + 0];
    gl[l] = (const float*)d_in[5 + (l - 1) * 3 + 1];
    bl[l] = (const float*)d_in[5 + (l - 1) * 3 + 2];
  }
  const float* Wfc = (const float*)d_in[26];
  float* out = (float*)d_out;

  const int* src = eidx;
  const int* tgt = eidx + NE;

  char* p = (char*)d_ws;
  auto alloc = [&](size_t bytes) -> void* {
    void* r = (void*)p;
    p += (bytes + 255) & ~(size_t)255;
    return r;
  };
  float* basis  = (float*)alloc((size_t)NE * 8 * 4);
  int*   widx   = (int*)  alloc((size_t)NE * 8 * 4);
  int*   deg    = (int*)  alloc((size_t)NN * 4);
  int*   row    = (int*)  alloc((size_t)(NN + 1) * 4);
  int*   cursor = (int*)  alloc((size_t)NN * 4);
  int*   perm   = (int*)  alloc((size_t)NE * 4);
  float* bufP   = (float*)alloc((size_t)NN * 128 * 4);
  float* bufQ   = (float*)alloc((size_t)NN * 128 * 4);
  float* bufR   = (float*)alloc((size_t)NN * 32 * 4);
  double* stats = (double*)alloc(256 * 8);
  int*   cl     = (int*)  alloc((size_t)NN * 4);
  float* cnt    = (float*)alloc((size_t)NCV * 4);
  float* posps  = (float*)alloc((size_t)NCV * 3 * 4);
  float* posp   = (float*)alloc((size_t)NCV * 3 * 4);
  float* validf = (float*)alloc((size_t)NCV * 4);
  float* xp     = (float*)alloc((size_t)NCV * 128 * 4);
  int*   marker = (int*)  alloc((size_t)NCV * NCV * 4);
  int*   nedge  = (int*)  alloc(256);
  unsigned int* amax = (unsigned int*)alloc(256);
  float* nvalid = (float*)alloc(256);
  int*   ce_s   = (int*)  alloc((size_t)NE * 4);
  int*   ce_d   = (int*)  alloc((size_t)NE * 4);
  float* basis2 = (float*)alloc((size_t)NE * 8 * 4);
  int*   widx2  = (int*)  alloc((size_t)NE * 8 * 4);
  int*   deg2   = (int*)  alloc((size_t)(NCV + 1) * 4);
  int*   pk_deg = (int*)  alloc(513 * 4);
  int*   pk_row = (int*)  alloc(513 * 4);
  int*   pk_cur = (int*)  alloc(512 * 4);
  float* num2   = (float*)alloc((size_t)NCV * 128 * 4);
  float* h2a    = (float*)alloc((size_t)NCV * 128 * 4);
  float* h2b    = (float*)alloc((size_t)NCV * 128 * 4);
  float* x7     = (float*)alloc((size_t)NSLOT * 128 * 4);
  float* cnt7   = (float*)alloc((size_t)NSLOT * 4);
  unsigned short* W5h = (unsigned short*)alloc((size_t)KT * 32 * 128 * 2);
  float* msg = (float*)alloc((size_t)NE * 128 * 4);

  // Y chunk: pick largest k-chunk that fits ws_size (constant across calls).
  size_t base = (size_t)(p - (char*)d_ws);
  int nk = 8;
  const int cands[] = {512, 256, 128, 64, 32, 16, 8};
  for (int c : cands) {
    if (base + (size_t)c * NCV * 128 * 4 <= ws_size) { nk = c; break; }
  }
  float* Y = (float*)alloc((size_t)nk * NCV * 128 * 4);

  // ---- init (ws is poisoned 0xAA before every call) ----
  hipMemsetAsync(deg, 0, (size_t)NN * 4, stream);
  hipMemsetAsync(cnt, 0, (size_t)NCV * 4, stream);
  hipMemsetAsync(posps, 0, (size_t)NCV * 3 * 4, stream);
  hipMemsetAsync(marker, 0, (size_t)NCV * NCV * 4, stream);
  hipMemsetAsync(nedge, 0, 4, stream);
  hipMemsetAsync(amax, 0, 4, stream);
  hipMemsetAsync(nvalid, 0, 4, stream);
  hipMemsetAsync(deg2, 0, (size_t)(NCV + 1) * 4, stream);
  hipMemsetAsync(cnt7, 0, (size_t)NSLOT * 4, stream);
  hipMemsetAsync(pk_deg, 0, 513 * 4, stream);
  k_fill<<<(NCV * 128 + 255) / 256, 256, 0, stream>>>(xp, -INFINITY, NCV * 128);
  k_fill<<<(NSLOT * 128 + 255) / 256, 256, 0, stream>>>(x7, -INFINITY, NSLOT * 128);

  // ---- weight prep ----
  k_wt5cvt<<<(KT * 32 * 128 + 255) / 256, 256, 0, stream>>>(Wl[5], W5h);

  // ---- fine graph prep ----
  k_spline<<<GE, 256, 0, stream>>>(eattr, basis, widx);
  k_hist<<<GE, 256, 0, stream>>>(tgt, deg, NE);
  k_scan<<<1, 256, 0, stream>>>(deg, row, cursor, NN);
  k_scatter<<<GE, 256, 0, stream>>>(tgt, cursor, perm, nullptr, NE);

  // ---- fine layers ----
  k_msg1<<<NE / 16, 256, 0, stream>>>(x_in, src, basis, widx, Wl[1], msg);
  k_agg<16><<<NN / 16, 256, 0, stream>>>(msg, perm, row, bufP, NN);
  hipMemsetAsync(stats, 0, 2 * 16 * 8, stream);
  k_bn_stats<16><<<64, 256, 0, stream>>>(bufP, nullptr, stats, NN);
  k_bn_norm<<<NN * 16 / 256, 256, 0, stream>>>(bufP, stats, nullptr, NN, gl[1], bl[1], nullptr, NN * 16, 15);

  k_msg_mid<16><<<NE / 8, 256, 0, stream>>>(bufP, src, basis, widx, Wl[2], msg);
  k_agg<32><<<NN / 8, 256, 0, stream>>>(msg, perm, row, bufQ, NN);
  hipMemsetAsync(stats, 0, 2 * 32 * 8, stream);
  k_bn_stats<32><<<64, 256, 0, stream>>>(bufQ, nullptr, stats, NN);
  k_bn_norm<<<NN * 32 / 256, 256, 0, stream>>>(bufQ, stats, nullptr, NN, gl[2], bl[2], nullptr, NN * 32, 31);

  k_msg_mid<32><<<NE / 8, 256, 0, stream>>>(bufQ, src, basis, widx, Wl[3], msg);
  k_agg<32><<<NN / 8, 256, 0, stream>>>(msg, perm, row, bufR, NN);
  hipMemsetAsync(stats, 0, 2 * 32 * 8, stream);
  k_bn_stats<32><<<64, 256, 0, stream>>>(bufR, nullptr, stats, NN);
  k_bn_norm<<<NN * 32 / 256, 256, 0, stream>>>(bufR, stats, nullptr, NN, gl[3], bl[3], nullptr, NN * 32, 31);

  k_msg_mid<32><<<NE / 8, 256, 0, stream>>>(bufR, src, basis, widx, Wl[4], msg);
  k_agg<32><<<NN / 8, 256, 0, stream>>>(msg, perm, row, bufP, NN);
  hipMemsetAsync(stats, 0, 2 * 32 * 8, stream);
  k_bn_stats<32><<<64, 256, 0, stream>>>(bufP, nullptr, stats, NN);
  k_bn_norm<<<NN * 32 / 256, 256, 0, stream>>>(bufP, stats, nullptr, NN, gl[4], bl[4], bufQ, NN * 32, 31);

  k_msg5<<<NE / 2, 256, 0, stream>>>(bufP, src, basis, widx, W5h, msg);
  k_agg<128><<<NN / 2, 256, 0, stream>>>(msg, perm, row, bufQ, NN);
  hipMemsetAsync(stats, 0, 2 * 128 * 8, stream);
  k_bn_stats<128><<<64, 256, 0, stream>>>(bufQ, nullptr, stats, NN);
  k_bn_norm<<<NN * 128 / 256, 256, 0, stream>>>(bufQ, stats, nullptr, NN, gl[5], bl[5], nullptr, NN * 128, 127);

  // ---- voxel max-pool ----
  k_pool5<<<NN * 128 / 256, 256, 0, stream>>>(bufQ, pos, batch, cl, cnt, posps, xp);
  k_pool5_fin<<<NCV * 128 / 256, 256, 0, stream>>>(xp, cnt, posps, posp, validf, nvalid);

  // ---- coarse edges ----
  k_claim<<<GE, 256, 0, stream>>>(src, tgt, cl, marker, ce_s, ce_d, nedge, deg2, amax, posp);
  k_spline2<<<GE, 256, 0, stream>>>(ce_s, ce_d, posp, amax, nedge, basis2, widx2);
  k_phist<<<GP, 256, 0, stream>>>(widx2, nedge, pk_deg);
  k_scan<<<1, 256, 0, stream>>>(pk_deg, pk_row, pk_cur, 512);

  // ---- coarse layer 6: xp -> h2a ----
  hipMemsetAsync(num2, 0, (size_t)NCV * 128 * 4, stream);
  for (int k0 = 0; k0 < KT; k0 += nk) {
    k_ygemm<<<8 * nk, 256, 0, stream>>>(xp, Wl[6], Y, pk_row, k0);
    k_gather2a<<<2048, 256, 0, stream>>>(Y, ce_s, ce_d, basis2, widx2, nedge, num2, k0, k0 + nk);
  }
  k_elu_div<<<NCV * 128 / 256, 256, 0, stream>>>(num2, deg2, h2a, NCV * 128);
  hipMemsetAsync(stats, 0, 2 * 128 * 8, stream);
  k_bn_stats<128><<<64, 256, 0, stream>>>(h2a, validf, stats, NCV);
  k_bn_norm<<<NCV * 128 / 256, 256, 0, stream>>>(h2a, stats, nvalid, NCV, gl[6], bl[6], nullptr, NCV * 128, 127);

  // ---- coarse layer 7: h2a -> h2b, then += xp ----
  hipMemsetAsync(num2, 0, (size_t)NCV * 128 * 4, stream);
  for (int k0 = 0; k0 < KT; k0 += nk) {
    k_ygemm<<<8 * nk, 256, 0, stream>>>(h2a, Wl[7], Y, pk_row, k0);
    k_gather2a<<<2048, 256, 0, stream>>>(Y, ce_s, ce_d, basis2, widx2, nedge, num2, k0, k0 + nk);
  }
  k_elu_div<<<NCV * 128 / 256, 256, 0, stream>>>(num2, deg2, h2b, NCV * 128);
  hipMemsetAsync(stats, 0, 2 * 128 * 8, stream);
  k_bn_stats<128><<<64, 256, 0, stream>>>(h2b, validf, stats, NCV);
  k_bn_norm<<<NCV * 128 / 256, 256, 0, stream>>>(h2b, stats, nvalid, NCV, gl[7], bl[7], xp, NCV * 128, 127);

  // ---- final pool + FC ----
  k_pool7<<<NCV * 128 / 256, 256, 0, stream>>>(h2b, posp, validf, x7, cnt7);
  k_x7fin<<<NSLOT * 128 / 256, 256, 0, stream>>>(x7, cnt7);
  k_fc<<<NB * NUM_OUT, 256, 0, stream>>>(x7, Wfc, out);
}

// Round 9
// 1262.402 us; speedup vs baseline: 1.3193x; 1.3193x over previous
//
#include <hip/hip_runtime.h>
#include <hip/hip_bf16.h>
#include <cstdint>
#include <cstddef>
#include <math.h>

// GraphResNet forward, round 9.
// Coarse gather: non-atomic two-step (edge-parallel k_msg2 -> target-sorted k_agg).
// R8's atomicAdd gather was memory-side-RMW bound (305MB writes for a 230KB buffer).
// k_ygemm skips empty spline bins. Fine convs unchanged (coalesced W, L5 bf16).

namespace {

constexpr int NB    = 2;
constexpr int NPER  = 4096;
constexpr int NN    = NB * NPER;        // 8192 nodes
constexpr int NE    = NN * 6;           // 49152 edges
constexpr int KT    = 512;              // 8^3 spline table
constexpr int NV5   = 225;
constexpr int NCV   = NB * NV5;         // 450 coarse voxels
constexpr int NSLOT = NB * 16;
constexpr int NUM_OUT = 11;
constexpr int GE    = (NE + 255) / 256;
constexpr int GP    = (NE * 8 + 255) / 256;

__device__ __forceinline__ void atomicMaxF(float* a, float v) {
  if (v >= 0.f) atomicMax((int*)a, __float_as_int(v));
  else          atomicMin((unsigned int*)a, __float_as_uint(v));
}

__device__ __forceinline__ float bfu(unsigned int u) { return __uint_as_float(u << 16); }

__device__ __forceinline__ void spline8(float p0, float p1, float p2, float* bas, int* idx) {
  float l0 = floorf(p0), l1 = floorf(p1), l2 = floorf(p2);
  float f0 = p0 - l0, f1 = p1 - l1, f2 = p2 - l2;
  int i0 = (int)l0, i1 = (int)l1, i2 = (int)l2;
#pragma unroll
  for (int s = 0; s < 8; ++s) {
    int b0 = s & 1, b1 = (s >> 1) & 1, b2 = (s >> 2) & 1;
    float w = (b0 ? f0 : 1.f - f0) * (b1 ? f1 : 1.f - f1) * (b2 ? f2 : 1.f - f2);
    int j0 = min(max(i0 + b0, 0), 7);
    int j1 = min(max(i1 + b1, 0), 7);
    int j2 = min(max(i2 + b2, 0), 7);
    bas[s] = w;
    idx[s] = j0 + (j1 << 3) + (j2 << 6);
  }
}

__global__ void k_fill(float* p, float v, int n) {
  int i = blockIdx.x * blockDim.x + threadIdx.x;
  if (i < n) p[i] = v;
}

__global__ void k_spline(const float* __restrict__ ea, float* __restrict__ basis,
                         int* __restrict__ widx) {
  int e = blockIdx.x * blockDim.x + threadIdx.x;
  if (e >= NE) return;
  float bas[8]; int idx[8];
  spline8(ea[e*3+0]*7.f, ea[e*3+1]*7.f, ea[e*3+2]*7.f, bas, idx);
#pragma unroll
  for (int s = 0; s < 8; ++s) { basis[e*8+s] = bas[s]; widx[e*8+s] = idx[s]; }
}

__global__ void k_hist(const int* __restrict__ t, int* deg, int n) {
  int i = blockIdx.x * blockDim.x + threadIdx.x;
  if (i < n) atomicAdd(&deg[t[i]], 1);
}

__global__ void k_scan(const int* __restrict__ deg, int* __restrict__ row,
                       int* __restrict__ cursor, int n) {
  __shared__ int part[256];
  int tid = threadIdx.x;
  int chunk = (n + 255) / 256;
  int s0 = tid * chunk, s1 = min(s0 + chunk, n);
  int s = 0;
  for (int i = s0; i < s1; ++i) s += deg[i];
  part[tid] = s;
  __syncthreads();
  for (int off = 1; off < 256; off <<= 1) {
    int v = (tid >= off) ? part[tid - off] : 0;
    __syncthreads();
    part[tid] += v;
    __syncthreads();
  }
  int run = (tid == 0) ? 0 : part[tid - 1];
  for (int i = s0; i < s1; ++i) { row[i] = run; cursor[i] = run; run += deg[i]; }
  if (tid == 255) row[n] = run;
}

__global__ void k_scatter(const int* __restrict__ t, int* cursor, int* __restrict__ perm,
                          const int* nptr, int nconst) {
  int n = nptr ? *nptr : nconst;
  int i = blockIdx.x * blockDim.x + threadIdx.x;
  if (i >= n) return;
  int pos = atomicAdd(&cursor[t[i]], 1);
  perm[pos] = i;
}

// ---- edge-parallel fine-conv messages (coalesced W reads) ----

__global__ __launch_bounds__(256)
void k_msg1(const float* __restrict__ x, const int* __restrict__ src,
            const float* __restrict__ basis, const int* __restrict__ widx,
            const float* __restrict__ W1, float* __restrict__ msg) {
  int e = blockIdx.x * 16 + (threadIdx.x >> 4);
  int f = threadIdx.x & 15;
  if (e >= NE) return;
  float xv = x[src[e]];
  float acc = 0.f;
#pragma unroll
  for (int b = 0; b < 8; ++b) {
    float bb = basis[e*8+b];
    int k = widx[e*8+b];
    acc += bb * W1[(size_t)k * 16 + f];
  }
  msg[(size_t)e * 16 + f] = acc * xv;
}

template<int CIN>
__global__ __launch_bounds__(256)
void k_msg_mid(const float* __restrict__ x, const int* __restrict__ src,
               const float* __restrict__ basis, const int* __restrict__ widx,
               const float* __restrict__ Wk, float* __restrict__ msg) {
  int e = blockIdx.x * 8 + (threadIdx.x >> 5);
  int f = threadIdx.x & 31;
  if (e >= NE) return;
  int s = src[e];
  float xv = (f < CIN) ? x[(size_t)s * CIN + f] : 0.f;
  float bs[8]; int ks[8];
#pragma unroll
  for (int b = 0; b < 8; ++b) { bs[b] = basis[e*8+b]; ks[b] = widx[e*8+b]; }
  float acc = 0.f;
#pragma unroll
  for (int b = 0; b < 8; ++b) {
    const float* Wp = Wk + (size_t)ks[b] * (CIN * 32) + f;
    float m = 0.f;
#pragma unroll
    for (int c = 0; c < CIN; ++c) m += __shfl(xv, c, 32) * Wp[c * 32];
    acc += bs[b] * m;
  }
  msg[(size_t)e * 32 + f] = acc;
}

__global__ __launch_bounds__(256)
void k_msg5(const float* __restrict__ x, const int* __restrict__ src,
            const float* __restrict__ basis, const int* __restrict__ widx,
            const unsigned short* __restrict__ W5h, float* __restrict__ msg) {
  __shared__ float xs[2][32];
  int sub = threadIdx.x >> 7;
  int f = threadIdx.x & 127;
  int e = blockIdx.x * 2 + sub;
  int s = src[e];
  if (f < 32) xs[sub][f] = x[(size_t)s * 32 + f];
  __syncthreads();
  float xv[32];
#pragma unroll
  for (int c = 0; c < 32; ++c) xv[c] = xs[sub][c];
  float bs[8]; int ks[8];
#pragma unroll
  for (int b = 0; b < 8; ++b) { bs[b] = basis[e*8+b]; ks[b] = widx[e*8+b]; }
  float acc = 0.f;
#pragma unroll
  for (int b = 0; b < 8; ++b) {
    const unsigned short* Wp = W5h + (size_t)ks[b] * 4096 + f;
    float m = 0.f;
#pragma unroll
    for (int c = 0; c < 32; ++c) m += xv[c] * bfu((unsigned int)Wp[c * 128]);
    acc += bs[b] * m;
  }
  msg[(size_t)e * 128 + f] = acc;
}

// aggregate edge messages per target (edges pre-sorted by target), fused mean+ELU.
template<int C>
__global__ __launch_bounds__(256)
void k_agg(const float* __restrict__ msg, const int* __restrict__ perm,
           const int* __restrict__ row, float* __restrict__ hout, int n) {
  constexpr int TPB = 256 / C;
  int t = blockIdx.x * TPB + threadIdx.x / C;
  int f = threadIdx.x % C;
  if (t >= n) return;
  int r0 = row[t], r1 = row[t + 1];
  float acc = 0.f;
  for (int i = r0; i < r1; ++i) acc += msg[(size_t)perm[i] * C + f];
  float h = acc / (float)max(r1 - r0, 1);
  hout[(size_t)t * C + f] = h > 0.f ? h : expm1f(h);
}

__global__ void k_wt5cvt(const float* __restrict__ W, unsigned short* __restrict__ Wh) {
  int i = blockIdx.x * 256 + threadIdx.x;
  if (i >= KT * 32 * 128) return;
  __hip_bfloat16 h = __float2bfloat16(W[i]);
  union { __hip_bfloat16 b; unsigned short u; } cv; cv.b = h;
  Wh[i] = cv.u;
}

// BN stats / norm
template<int C>
__global__ void k_bn_stats(const float* __restrict__ h, const float* __restrict__ maskf,
                           double* __restrict__ stats, int n) {
  constexpr int RPB = 256 / C;
  int f = threadIdx.x % C;
  int r = threadIdx.x / C;
  float s = 0.f, ss = 0.f;
  for (int i = blockIdx.x * RPB + r; i < n; i += gridDim.x * RPB) {
    float v = h[(size_t)i * C + f];
    if (maskf) v *= maskf[i];
    s += v; ss += v * v;
  }
  __shared__ float ls[256], lss[256];
  ls[threadIdx.x] = s; lss[threadIdx.x] = ss;
  __syncthreads();
  if (r == 0) {
#pragma unroll
    for (int j = 1; j < RPB; ++j) { s += ls[j * C + f]; ss += lss[j * C + f]; }
    atomicAdd(&stats[f], (double)s);
    atomicAdd(&stats[C + f], (double)ss);
  }
}

__global__ void k_bn_norm(float* __restrict__ h, const double* __restrict__ stats,
                          const float* cntp, int defn, const float* __restrict__ g,
                          const float* __restrict__ b, const float* __restrict__ sc,
                          int total, int Cmask) {
  int i = blockIdx.x * blockDim.x + threadIdx.x;
  if (i >= total) return;
  int f = i & Cmask;
  double cnt = cntp ? (double)fmaxf(*cntp, 1.f) : (double)defn;
  double m = stats[f] / cnt;
  double v = stats[(Cmask + 1) + f] / cnt - m * m;
  float inv = rsqrtf((float)v + 1e-5f);
  float val = (h[i] - (float)m) * inv * g[f] + b[f];
  if (sc) val += sc[i];
  h[i] = val;
}

// pooling / coarse graph construction
__global__ void k_pool5(const float* __restrict__ h, const float* __restrict__ pos,
                        const int* __restrict__ batch, int* __restrict__ cl,
                        float* cnt, float* posps, float* xp) {
  int i = blockIdx.x * blockDim.x + threadIdx.x;
  if (i >= NN * 128) return;
  int node = i >> 7, f = i & 127;
  float px = pos[node*3+0], py = pos[node*3+1];
  int vx = min(max((int)floorf(px / 16.f), 0), 14);
  int vy = min(max((int)floorf(py / 12.f), 0), 14);
  int c = batch[node] * NV5 + vy * 15 + vx;
  if (f == 0) { cl[node] = c; atomicAdd(&cnt[c], 1.f); }
  if (f < 3) atomicAdd(&posps[c*3+f], pos[node*3+f]);
  atomicMaxF(&xp[(size_t)c * 128 + f], h[(size_t)node * 128 + f]);
}

__global__ void k_pool5_fin(float* xp, const float* __restrict__ cnt,
                            const float* __restrict__ posps, float* posp,
                            float* validf, float* nvalid) {
  int i = blockIdx.x * blockDim.x + threadIdx.x;
  if (i >= NCV * 128) return;
  int c = i >> 7, f = i & 127;
  bool val = cnt[c] > 0.f;
  if (f == 0) { validf[c] = val ? 1.f : 0.f; if (val) atomicAdd(nvalid, 1.f); }
  if (f < 3) posp[c*3+f] = posps[c*3+f] / fmaxf(cnt[c], 1.f);
  xp[i] = val ? xp[i] : 0.f;
}

__global__ void k_claim(const int* __restrict__ src, const int* __restrict__ tgt,
                        const int* __restrict__ cl, int* marker, int* ce_s, int* ce_d,
                        int* nedge, int* deg2, unsigned int* amax,
                        const float* __restrict__ posp) {
  int e = blockIdx.x * blockDim.x + threadIdx.x;
  if (e >= NE) return;
  int cs = cl[src[e]], ct = cl[tgt[e]];
  int key = cs * NCV + ct;
  if (atomicCAS(&marker[key], 0, 1) == 0 && cs != ct) {
    int id = atomicAdd(nedge, 1);
    ce_s[id] = cs; ce_d[id] = ct;
    atomicAdd(&deg2[ct], 1);
#pragma unroll
    for (int d = 0; d < 3; ++d) {
      float a = fabsf(posp[cs*3+d] - posp[ct*3+d]);
      atomicMax(amax, __float_as_uint(a));
    }
  }
}

__global__ void k_spline2(const int* __restrict__ ce_s, const int* __restrict__ ce_d,
                          const float* __restrict__ posp, const unsigned int* amaxp,
                          const int* nedgep, float* __restrict__ basis2,
                          int* __restrict__ widx2) {
  int i = blockIdx.x * blockDim.x + threadIdx.x;
  if (i >= *nedgep) return;
  float am = __uint_as_float(*amaxp);
  float den = 2.f * am + 1e-12f;
  int cs = ce_s[i], ct = ce_d[i];
  float p[3];
#pragma unroll
  for (int d = 0; d < 3; ++d) {
    float cart = posp[cs*3+d] - posp[ct*3+d];
    float ps = cart / den + 0.5f;
    ps = fminf(fmaxf(ps, 0.f), 1.f);
    p[d] = ps * 7.f;
  }
  float bas[8]; int idx[8];
  spline8(p[0], p[1], p[2], bas, idx);
#pragma unroll
  for (int s = 0; s < 8; ++s) { basis2[i*8+s] = bas[s]; widx2[i*8+s] = idx[s]; }
}

// histogram of pair spline-indices (to skip empty k bins in ygemm)
__global__ void k_phist(const int* __restrict__ widx2, const int* nedgep, int* pk_deg) {
  int i = blockIdx.x * blockDim.x + threadIdx.x;
  if (i >= 8 * (*nedgep)) return;
  atomicAdd(&pk_deg[widx2[i]], 1);
}

// batched Y[kk] = X(450x128) @ W[k0+kk](128x128); skips bins with no pairs.
__global__ __launch_bounds__(256)
void k_ygemm(const float* __restrict__ X, const float* __restrict__ Wk,
             float* __restrict__ Y, const int* __restrict__ pk_row, int k0) {
  int tile = blockIdx.x & 7;
  int kk = blockIdx.x >> 3;
  int k = k0 + kk;
  if (pk_row[k + 1] == pk_row[k]) return;   // no pairs use this bin
  int n0 = tile * 64;
  __shared__ float Xs[64][32];
  __shared__ float Ws[32][128];
  int tid = threadIdx.x;
  int tx = tid & 31;
  int ty = tid >> 5;
  float acc[8][4];
#pragma unroll
  for (int i = 0; i < 8; ++i)
#pragma unroll
    for (int j = 0; j < 4; ++j) acc[i][j] = 0.f;
  for (int c0 = 0; c0 < 128; c0 += 32) {
    for (int idx = tid; idx < 64 * 32; idx += 256) {
      int n = idx >> 5, c = idx & 31;
      int gn = n0 + n;
      Xs[n][c] = (gn < NCV) ? X[(size_t)gn * 128 + c0 + c] : 0.f;
    }
    for (int idx = tid; idx < 32 * 128; idx += 256) {
      int c = idx >> 7, f = idx & 127;
      Ws[c][f] = Wk[((size_t)k * 128 + c0 + c) * 128 + f];
    }
    __syncthreads();
#pragma unroll 8
    for (int c = 0; c < 32; ++c) {
      float4 wv = *(const float4*)&Ws[c][tx * 4];
#pragma unroll
      for (int i = 0; i < 8; ++i) {
        float xv = Xs[ty * 8 + i][c];
        acc[i][0] += xv * wv.x; acc[i][1] += xv * wv.y;
        acc[i][2] += xv * wv.z; acc[i][3] += xv * wv.w;
      }
    }
    __syncthreads();
  }
#pragma unroll
  for (int i = 0; i < 8; ++i) {
    int gn = n0 + ty * 8 + i;
    if (gn < NCV) {
      float4 v = make_float4(acc[i][0], acc[i][1], acc[i][2], acc[i][3]);
      *(float4*)&Y[((size_t)kk * NCV + gn) * 128 + tx * 4] = v;
    }
  }
}

// edge-parallel coarse messages: msg[e][f] (+)= sum_b basis*Y[k_b][src][f], k in [k0,k1)
__global__ __launch_bounds__(256)
void k_msg2(const float* __restrict__ Y, const int* __restrict__ ce_s,
            const float* __restrict__ basis2, const int* __restrict__ widx2,
            const int* nedgep, float* __restrict__ msg, int k0, int k1, int first) {
  int sub = threadIdx.x >> 7;
  int f = threadIdx.x & 127;
  int e = blockIdx.x * 2 + sub;
  if (e >= *nedgep) return;
  int s = ce_s[e];
  float acc = first ? 0.f : msg[(size_t)e * 128 + f];
#pragma unroll
  for (int b = 0; b < 8; ++b) {
    int k = widx2[e*8+b];
    if (k >= k0 && k < k1)
      acc += basis2[e*8+b] * Y[((size_t)(k - k0) * NCV + s) * 128 + f];
  }
  msg[(size_t)e * 128 + f] = acc;
}

__global__ void k_pool7(const float* __restrict__ h2, const float* __restrict__ posp,
                        const float* __restrict__ validf, float* x7, float* cnt7) {
  int i = blockIdx.x * blockDim.x + threadIdx.x;
  if (i >= NCV * 128) return;
  int c = i >> 7, f = i & 127;
  bool val = validf[c] > 0.f;
  float hv = val ? h2[i] : -1e30f;
  float px = posp[c*3+0], py = posp[c*3+1];
  int vx = min(max((int)floorf(px / 60.f), 0), 3);
  int vy = min(max((int)floorf(py / 45.f), 0), 3);
  int s = (c / NV5) * 16 + vy * 4 + vx;
  atomicMaxF(&x7[(size_t)s * 128 + f], hv);
  if (f == 0) atomicAdd(&cnt7[s], validf[c]);
}

__global__ void k_x7fin(float* x7, const float* __restrict__ cnt7) {
  int i = blockIdx.x * blockDim.x + threadIdx.x;
  if (i >= NSLOT * 128) return;
  x7[i] = (cnt7[i >> 7] > 0.f) ? x7[i] : 0.f;
}

__global__ void k_fc(const float* __restrict__ x7, const float* __restrict__ Wfc,
                     float* __restrict__ out) {
  int bid = blockIdx.x;
  int s = bid / NUM_OUT, o = bid % NUM_OUT;
  float p = 0.f;
  for (int j = threadIdx.x; j < 16 * 128; j += 256)
    p += x7[(size_t)s * 2048 + j] * Wfc[(size_t)o * 2048 + j];
  __shared__ float red[256];
  red[threadIdx.x] = p;
  __syncthreads();
  for (int st = 128; st > 0; st >>= 1) {
    if (threadIdx.x < st) red[threadIdx.x] += red[threadIdx.x + st];
    __syncthreads();
  }
  if (threadIdx.x == 0) out[s * NUM_OUT + o] = red[0];
}

} // namespace

extern "C" void kernel_launch(void* const* d_in, const int* in_sizes, int n_in,
                              void* d_out, int out_size, void* d_ws, size_t ws_size,
                              hipStream_t stream) {
  (void)in_sizes; (void)n_in; (void)out_size;
  const float* x_in  = (const float*)d_in[0];
  const float* pos   = (const float*)d_in[1];
  const float* eattr = (const float*)d_in[2];
  const int*   eidx  = (const int*)d_in[3];
  const int*   batch = (const int*)d_in[4];
  const float *Wl[8], *gl[8], *bl[8];
  for (int l = 1; l <= 7; ++l) {
    Wl[l] = (const float*)d_in[5 + (l - 1) * 3 + 0];
    gl[l] = (const float*)d_in[5 + (l - 1) * 3 + 1];
    bl[l] = (const float*)d_in[5 + (l - 1) * 3 + 2];
  }
  const float* Wfc = (const float*)d_in[26];
  float* out = (float*)d_out;

  const int* src = eidx;
  const int* tgt = eidx + NE;

  char* p = (char*)d_ws;
  auto alloc = [&](size_t bytes) -> void* {
    void* r = (void*)p;
    p += (bytes + 255) & ~(size_t)255;
    return r;
  };
  float* basis  = (float*)alloc((size_t)NE * 8 * 4);
  int*   widx   = (int*)  alloc((size_t)NE * 8 * 4);
  int*   deg    = (int*)  alloc((size_t)NN * 4);
  int*   row    = (int*)  alloc((size_t)(NN + 1) * 4);
  int*   cursor = (int*)  alloc((size_t)NN * 4);
  int*   perm   = (int*)  alloc((size_t)NE * 4);
  float* bufP   = (float*)alloc((size_t)NN * 128 * 4);
  float* bufQ   = (float*)alloc((size_t)NN * 128 * 4);
  float* bufR   = (float*)alloc((size_t)NN * 32 * 4);
  double* stats = (double*)alloc(256 * 8);
  int*   cl     = (int*)  alloc((size_t)NN * 4);
  float* cnt    = (float*)alloc((size_t)NCV * 4);
  float* posps  = (float*)alloc((size_t)NCV * 3 * 4);
  float* posp   = (float*)alloc((size_t)NCV * 3 * 4);
  float* validf = (float*)alloc((size_t)NCV * 4);
  float* xp     = (float*)alloc((size_t)NCV * 128 * 4);
  int*   marker = (int*)  alloc((size_t)NCV * NCV * 4);
  int*   nedge  = (int*)  alloc(256);
  unsigned int* amax = (unsigned int*)alloc(256);
  float* nvalid = (float*)alloc(256);
  int*   ce_s   = (int*)  alloc((size_t)NE * 4);
  int*   ce_d   = (int*)  alloc((size_t)NE * 4);
  float* basis2 = (float*)alloc((size_t)NE * 8 * 4);
  int*   widx2  = (int*)  alloc((size_t)NE * 8 * 4);
  int*   deg2   = (int*)  alloc((size_t)(NCV + 1) * 4);
  int*   row2   = (int*)  alloc((size_t)(NCV + 1) * 4);
  int*   cur2   = (int*)  alloc((size_t)NCV * 4);
  int*   perm2  = (int*)  alloc((size_t)NE * 4);
  int*   pk_deg = (int*)  alloc(513 * 4);
  int*   pk_row = (int*)  alloc(513 * 4);
  int*   pk_cur = (int*)  alloc(512 * 4);
  float* h2a    = (float*)alloc((size_t)NCV * 128 * 4);
  float* h2b    = (float*)alloc((size_t)NCV * 128 * 4);
  float* x7     = (float*)alloc((size_t)NSLOT * 128 * 4);
  float* cnt7   = (float*)alloc((size_t)NSLOT * 4);
  unsigned short* W5h = (unsigned short*)alloc((size_t)KT * 32 * 128 * 2);
  float* msg = (float*)alloc((size_t)NE * 128 * 4);

  // Y chunk: pick largest k-chunk that fits ws_size (constant across calls).
  size_t base = (size_t)(p - (char*)d_ws);
  int nk = 8;
  const int cands[] = {512, 256, 128, 64, 32, 16, 8};
  for (int c : cands) {
    if (base + (size_t)c * NCV * 128 * 4 <= ws_size) { nk = c; break; }
  }
  float* Y = (float*)alloc((size_t)nk * NCV * 128 * 4);

  // ---- init (ws is poisoned 0xAA before every call) ----
  hipMemsetAsync(deg, 0, (size_t)NN * 4, stream);
  hipMemsetAsync(cnt, 0, (size_t)NCV * 4, stream);
  hipMemsetAsync(posps, 0, (size_t)NCV * 3 * 4, stream);
  hipMemsetAsync(marker, 0, (size_t)NCV * NCV * 4, stream);
  hipMemsetAsync(nedge, 0, 4, stream);
  hipMemsetAsync(amax, 0, 4, stream);
  hipMemsetAsync(nvalid, 0, 4, stream);
  hipMemsetAsync(deg2, 0, (size_t)(NCV + 1) * 4, stream);
  hipMemsetAsync(cnt7, 0, (size_t)NSLOT * 4, stream);
  hipMemsetAsync(pk_deg, 0, 513 * 4, stream);
  k_fill<<<(NCV * 128 + 255) / 256, 256, 0, stream>>>(xp, -INFINITY, NCV * 128);
  k_fill<<<(NSLOT * 128 + 255) / 256, 256, 0, stream>>>(x7, -INFINITY, NSLOT * 128);

  // ---- weight prep ----
  k_wt5cvt<<<(KT * 32 * 128 + 255) / 256, 256, 0, stream>>>(Wl[5], W5h);

  // ---- fine graph prep ----
  k_spline<<<GE, 256, 0, stream>>>(eattr, basis, widx);
  k_hist<<<GE, 256, 0, stream>>>(tgt, deg, NE);
  k_scan<<<1, 256, 0, stream>>>(deg, row, cursor, NN);
  k_scatter<<<GE, 256, 0, stream>>>(tgt, cursor, perm, nullptr, NE);

  // ---- fine layers ----
  k_msg1<<<NE / 16, 256, 0, stream>>>(x_in, src, basis, widx, Wl[1], msg);
  k_agg<16><<<NN / 16, 256, 0, stream>>>(msg, perm, row, bufP, NN);
  hipMemsetAsync(stats, 0, 2 * 16 * 8, stream);
  k_bn_stats<16><<<64, 256, 0, stream>>>(bufP, nullptr, stats, NN);
  k_bn_norm<<<NN * 16 / 256, 256, 0, stream>>>(bufP, stats, nullptr, NN, gl[1], bl[1], nullptr, NN * 16, 15);

  k_msg_mid<16><<<NE / 8, 256, 0, stream>>>(bufP, src, basis, widx, Wl[2], msg);
  k_agg<32><<<NN / 8, 256, 0, stream>>>(msg, perm, row, bufQ, NN);
  hipMemsetAsync(stats, 0, 2 * 32 * 8, stream);
  k_bn_stats<32><<<64, 256, 0, stream>>>(bufQ, nullptr, stats, NN);
  k_bn_norm<<<NN * 32 / 256, 256, 0, stream>>>(bufQ, stats, nullptr, NN, gl[2], bl[2], nullptr, NN * 32, 31);

  k_msg_mid<32><<<NE / 8, 256, 0, stream>>>(bufQ, src, basis, widx, Wl[3], msg);
  k_agg<32><<<NN / 8, 256, 0, stream>>>(msg, perm, row, bufR, NN);
  hipMemsetAsync(stats, 0, 2 * 32 * 8, stream);
  k_bn_stats<32><<<64, 256, 0, stream>>>(bufR, nullptr, stats, NN);
  k_bn_norm<<<NN * 32 / 256, 256, 0, stream>>>(bufR, stats, nullptr, NN, gl[3], bl[3], nullptr, NN * 32, 31);

  k_msg_mid<32><<<NE / 8, 256, 0, stream>>>(bufR, src, basis, widx, Wl[4], msg);
  k_agg<32><<<NN / 8, 256, 0, stream>>>(msg, perm, row, bufP, NN);
  hipMemsetAsync(stats, 0, 2 * 32 * 8, stream);
  k_bn_stats<32><<<64, 256, 0, stream>>>(bufP, nullptr, stats, NN);
  k_bn_norm<<<NN * 32 / 256, 256, 0, stream>>>(bufP, stats, nullptr, NN, gl[4], bl[4], bufQ, NN * 32, 31);

  k_msg5<<<NE / 2, 256, 0, stream>>>(bufP, src, basis, widx, W5h, msg);
  k_agg<128><<<NN / 2, 256, 0, stream>>>(msg, perm, row, bufQ, NN);
  hipMemsetAsync(stats, 0, 2 * 128 * 8, stream);
  k_bn_stats<128><<<64, 256, 0, stream>>>(bufQ, nullptr, stats, NN);
  k_bn_norm<<<NN * 128 / 256, 256, 0, stream>>>(bufQ, stats, nullptr, NN, gl[5], bl[5], nullptr, NN * 128, 127);

  // ---- voxel max-pool ----
  k_pool5<<<NN * 128 / 256, 256, 0, stream>>>(bufQ, pos, batch, cl, cnt, posps, xp);
  k_pool5_fin<<<NCV * 128 / 256, 256, 0, stream>>>(xp, cnt, posps, posp, validf, nvalid);

  // ---- coarse edges ----
  k_claim<<<GE, 256, 0, stream>>>(src, tgt, cl, marker, ce_s, ce_d, nedge, deg2, amax, posp);
  k_spline2<<<GE, 256, 0, stream>>>(ce_s, ce_d, posp, amax, nedge, basis2, widx2);
  k_phist<<<GP, 256, 0, stream>>>(widx2, nedge, pk_deg);
  k_scan<<<1, 256, 0, stream>>>(deg2, row2, cur2, NCV);
  k_scatter<<<GE, 256, 0, stream>>>(ce_d, cur2, perm2, nedge, 0);
  k_scan<<<1, 256, 0, stream>>>(pk_deg, pk_row, pk_cur, 512);

  // ---- coarse layer 6: xp -> h2a ----
  for (int k0 = 0; k0 < KT; k0 += nk) {
    k_ygemm<<<8 * nk, 256, 0, stream>>>(xp, Wl[6], Y, pk_row, k0);
    k_msg2<<<NE / 2, 256, 0, stream>>>(Y, ce_s, basis2, widx2, nedge, msg, k0, k0 + nk, k0 == 0 ? 1 : 0);
  }
  k_agg<128><<<NCV / 2 + 1, 256, 0, stream>>>(msg, perm2, row2, h2a, NCV);
  hipMemsetAsync(stats, 0, 2 * 128 * 8, stream);
  k_bn_stats<128><<<64, 256, 0, stream>>>(h2a, validf, stats, NCV);
  k_bn_norm<<<NCV * 128 / 256, 256, 0, stream>>>(h2a, stats, nvalid, NCV, gl[6], bl[6], nullptr, NCV * 128, 127);

  // ---- coarse layer 7: h2a -> h2b, then += xp ----
  for (int k0 = 0; k0 < KT; k0 += nk) {
    k_ygemm<<<8 * nk, 256, 0, stream>>>(h2a, Wl[7], Y, pk_row, k0);
    k_msg2<<<NE / 2, 256, 0, stream>>>(Y, ce_s, basis2, widx2, nedge, msg, k0, k0 + nk, k0 == 0 ? 1 : 0);
  }
  k_agg<128><<<NCV / 2 + 1, 256, 0, stream>>>(msg, perm2, row2, h2b, NCV);
  hipMemsetAsync(stats, 0, 2 * 128 * 8, stream);
  k_bn_stats<128><<<64, 256, 0, stream>>>(h2b, validf, stats, NCV);
  k_bn_norm<<<NCV * 128 / 256, 256, 0, stream>>>(h2b, stats, nvalid, NCV, gl[7], bl[7], xp, NCV * 128, 127);

  // ---- final pool + FC ----
  k_pool7<<<NCV * 128 / 256, 256, 0, stream>>>(h2b, posp, validf, x7, cnt7);
  k_x7fin<<<NSLOT * 128 / 256, 256, 0, stream>>>(x7, cnt7);
  k_fc<<<NB * NUM_OUT, 256, 0, stream>>>(x7, Wfc, out);
}

// Round 10
// 1148.708 us; speedup vs baseline: 1.4499x; 1.0990x over previous
//
#include <hip/hip_runtime.h>
#include <hip/hip_bf16.h>
#include <cstdint>
#include <cstddef>
#include <math.h>

// GraphResNet forward, round 10.
// Fine conv weights now bf16 PACKED (2 cin per uint32): halves L2 bytes and load
// instructions vs R9; dual accumulators break the serial FMA chain. Coarse stage
// unchanged from R9 (ygemm with empty-bin skip + edge-parallel msg2 + sorted agg).

namespace {

constexpr int NB    = 2;
constexpr int NPER  = 4096;
constexpr int NN    = NB * NPER;        // 8192 nodes
constexpr int NE    = NN * 6;           // 49152 edges
constexpr int KT    = 512;              // 8^3 spline table
constexpr int NV5   = 225;
constexpr int NCV   = NB * NV5;         // 450 coarse voxels
constexpr int NSLOT = NB * 16;
constexpr int NUM_OUT = 11;
constexpr int GE    = (NE + 255) / 256;
constexpr int GP    = (NE * 8 + 255) / 256;

__device__ __forceinline__ void atomicMaxF(float* a, float v) {
  if (v >= 0.f) atomicMax((int*)a, __float_as_int(v));
  else          atomicMin((unsigned int*)a, __float_as_uint(v));
}

__device__ __forceinline__ float bfLO(unsigned int u) { return __uint_as_float(u << 16); }
__device__ __forceinline__ float bfHI(unsigned int u) { return __uint_as_float(u & 0xffff0000u); }

__device__ __forceinline__ void spline8(float p0, float p1, float p2, float* bas, int* idx) {
  float l0 = floorf(p0), l1 = floorf(p1), l2 = floorf(p2);
  float f0 = p0 - l0, f1 = p1 - l1, f2 = p2 - l2;
  int i0 = (int)l0, i1 = (int)l1, i2 = (int)l2;
#pragma unroll
  for (int s = 0; s < 8; ++s) {
    int b0 = s & 1, b1 = (s >> 1) & 1, b2 = (s >> 2) & 1;
    float w = (b0 ? f0 : 1.f - f0) * (b1 ? f1 : 1.f - f1) * (b2 ? f2 : 1.f - f2);
    int j0 = min(max(i0 + b0, 0), 7);
    int j1 = min(max(i1 + b1, 0), 7);
    int j2 = min(max(i2 + b2, 0), 7);
    bas[s] = w;
    idx[s] = j0 + (j1 << 3) + (j2 << 6);
  }
}

__global__ void k_fill(float* p, float v, int n) {
  int i = blockIdx.x * blockDim.x + threadIdx.x;
  if (i < n) p[i] = v;
}

__global__ void k_spline(const float* __restrict__ ea, float* __restrict__ basis,
                         int* __restrict__ widx) {
  int e = blockIdx.x * blockDim.x + threadIdx.x;
  if (e >= NE) return;
  float bas[8]; int idx[8];
  spline8(ea[e*3+0]*7.f, ea[e*3+1]*7.f, ea[e*3+2]*7.f, bas, idx);
#pragma unroll
  for (int s = 0; s < 8; ++s) { basis[e*8+s] = bas[s]; widx[e*8+s] = idx[s]; }
}

__global__ void k_hist(const int* __restrict__ t, int* deg, int n) {
  int i = blockIdx.x * blockDim.x + threadIdx.x;
  if (i < n) atomicAdd(&deg[t[i]], 1);
}

__global__ void k_scan(const int* __restrict__ deg, int* __restrict__ row,
                       int* __restrict__ cursor, int n) {
  __shared__ int part[256];
  int tid = threadIdx.x;
  int chunk = (n + 255) / 256;
  int s0 = tid * chunk, s1 = min(s0 + chunk, n);
  int s = 0;
  for (int i = s0; i < s1; ++i) s += deg[i];
  part[tid] = s;
  __syncthreads();
  for (int off = 1; off < 256; off <<= 1) {
    int v = (tid >= off) ? part[tid - off] : 0;
    __syncthreads();
    part[tid] += v;
    __syncthreads();
  }
  int run = (tid == 0) ? 0 : part[tid - 1];
  for (int i = s0; i < s1; ++i) { row[i] = run; cursor[i] = run; run += deg[i]; }
  if (tid == 255) row[n] = run;
}

__global__ void k_scatter(const int* __restrict__ t, int* cursor, int* __restrict__ perm,
                          const int* nptr, int nconst) {
  int n = nptr ? *nptr : nconst;
  int i = blockIdx.x * blockDim.x + threadIdx.x;
  if (i >= n) return;
  int pos = atomicAdd(&cursor[t[i]], 1);
  perm[pos] = i;
}

// pack W[k][c][COUT] (f32) -> Wp[k][c/2][COUT] (two bf16 per uint: lo=c even, hi=c odd)
template<int CIN, int COUT>
__global__ void k_wpack(const float* __restrict__ W, unsigned int* __restrict__ Wp) {
  int i = blockIdx.x * 256 + threadIdx.x;
  if (i >= KT * (CIN / 2) * COUT) return;
  int k = i / ((CIN / 2) * COUT);
  int r = i % ((CIN / 2) * COUT);
  int c2 = r / COUT, f = r % COUT;
  float lo = W[((size_t)k * CIN + 2 * c2) * COUT + f];
  float hi = W[((size_t)k * CIN + 2 * c2 + 1) * COUT + f];
  union { __hip_bfloat16 b; unsigned short u; } cl, ch;
  cl.b = __float2bfloat16(lo); ch.b = __float2bfloat16(hi);
  Wp[i] = (unsigned int)cl.u | ((unsigned int)ch.u << 16);
}

// ---- edge-parallel fine-conv messages ----

// L1 (1->16): f32 weights (tiny table).
__global__ __launch_bounds__(256)
void k_msg1(const float* __restrict__ x, const int* __restrict__ src,
            const float* __restrict__ basis, const int* __restrict__ widx,
            const float* __restrict__ W1, float* __restrict__ msg) {
  int e = blockIdx.x * 16 + (threadIdx.x >> 4);
  int f = threadIdx.x & 15;
  if (e >= NE) return;
  float xv = x[src[e]];
  float acc = 0.f;
#pragma unroll
  for (int b = 0; b < 8; ++b) {
    float bb = basis[e*8+b];
    int k = widx[e*8+b];
    acc += bb * W1[(size_t)k * 16 + f];
  }
  msg[(size_t)e * 16 + f] = acc * xv;
}

// mid (CIN->32): packed bf16 weights; lane f reads uint (2 cin) -> coalesced 128B/instr.
template<int CIN>
__global__ __launch_bounds__(256)
void k_msg_mid(const float* __restrict__ x, const int* __restrict__ src,
               const float* __restrict__ basis, const int* __restrict__ widx,
               const unsigned int* __restrict__ Wp, float* __restrict__ msg) {
  int e = blockIdx.x * 8 + (threadIdx.x >> 5);
  int f = threadIdx.x & 31;
  if (e >= NE) return;
  int s = src[e];
  float xv = (f < CIN) ? x[(size_t)s * CIN + f] : 0.f;
  float bs[8]; int ks[8];
#pragma unroll
  for (int b = 0; b < 8; ++b) { bs[b] = basis[e*8+b]; ks[b] = widx[e*8+b]; }
  float acc0 = 0.f, acc1 = 0.f;
#pragma unroll
  for (int b = 0; b < 8; ++b) {
    const unsigned int* P = Wp + (size_t)ks[b] * (CIN / 2 * 32) + f;
    float m0 = 0.f, m1 = 0.f;
#pragma unroll
    for (int c2 = 0; c2 < CIN / 2; ++c2) {
      unsigned int u = P[c2 * 32];
      m0 += __shfl(xv, 2 * c2, 32) * bfLO(u);
      m1 += __shfl(xv, 2 * c2 + 1, 32) * bfHI(u);
    }
    acc0 += bs[b] * m0; acc1 += bs[b] * m1;
  }
  msg[(size_t)e * 32 + f] = acc0 + acc1;
}

// L5 (32->128): packed bf16 [k][16][128]; lane f reads uint (2 cin) = 512B/instr.
__global__ __launch_bounds__(256)
void k_msg5(const float* __restrict__ x, const int* __restrict__ src,
            const float* __restrict__ basis, const int* __restrict__ widx,
            const unsigned int* __restrict__ W5p, float* __restrict__ msg) {
  __shared__ float xs[2][32];
  int sub = threadIdx.x >> 7;
  int f = threadIdx.x & 127;
  int e = blockIdx.x * 2 + sub;
  int s = src[e];
  if (f < 32) xs[sub][f] = x[(size_t)s * 32 + f];
  __syncthreads();
  float xv[32];
#pragma unroll
  for (int c = 0; c < 32; ++c) xv[c] = xs[sub][c];
  float bs[8]; int ks[8];
#pragma unroll
  for (int b = 0; b < 8; ++b) { bs[b] = basis[e*8+b]; ks[b] = widx[e*8+b]; }
  float acc0 = 0.f, acc1 = 0.f;
#pragma unroll
  for (int b = 0; b < 8; ++b) {
    const unsigned int* P = W5p + (size_t)ks[b] * 2048 + f;
    float m0 = 0.f, m1 = 0.f;
#pragma unroll
    for (int c2 = 0; c2 < 16; ++c2) {
      unsigned int u = P[c2 * 128];
      m0 += xv[2 * c2] * bfLO(u);
      m1 += xv[2 * c2 + 1] * bfHI(u);
    }
    acc0 += bs[b] * m0; acc1 += bs[b] * m1;
  }
  msg[(size_t)e * 128 + f] = acc0 + acc1;
}

// aggregate edge messages per target (edges pre-sorted by target), fused mean+ELU.
template<int C>
__global__ __launch_bounds__(256)
void k_agg(const float* __restrict__ msg, const int* __restrict__ perm,
           const int* __restrict__ row, float* __restrict__ hout, int n) {
  constexpr int TPB = 256 / C;
  int t = blockIdx.x * TPB + threadIdx.x / C;
  int f = threadIdx.x % C;
  if (t >= n) return;
  int r0 = row[t], r1 = row[t + 1];
  float acc = 0.f;
  for (int i = r0; i < r1; ++i) acc += msg[(size_t)perm[i] * C + f];
  float h = acc / (float)max(r1 - r0, 1);
  hout[(size_t)t * C + f] = h > 0.f ? h : expm1f(h);
}

// BN stats / norm
template<int C>
__global__ void k_bn_stats(const float* __restrict__ h, const float* __restrict__ maskf,
                           double* __restrict__ stats, int n) {
  constexpr int RPB = 256 / C;
  int f = threadIdx.x % C;
  int r = threadIdx.x / C;
  float s = 0.f, ss = 0.f;
  for (int i = blockIdx.x * RPB + r; i < n; i += gridDim.x * RPB) {
    float v = h[(size_t)i * C + f];
    if (maskf) v *= maskf[i];
    s += v; ss += v * v;
  }
  __shared__ float ls[256], lss[256];
  ls[threadIdx.x] = s; lss[threadIdx.x] = ss;
  __syncthreads();
  if (r == 0) {
#pragma unroll
    for (int j = 1; j < RPB; ++j) { s += ls[j * C + f]; ss += lss[j * C + f]; }
    atomicAdd(&stats[f], (double)s);
    atomicAdd(&stats[C + f], (double)ss);
  }
}

__global__ void k_bn_norm(float* __restrict__ h, const double* __restrict__ stats,
                          const float* cntp, int defn, const float* __restrict__ g,
                          const float* __restrict__ b, const float* __restrict__ sc,
                          int total, int Cmask) {
  int i = blockIdx.x * blockDim.x + threadIdx.x;
  if (i >= total) return;
  int f = i & Cmask;
  double cnt = cntp ? (double)fmaxf(*cntp, 1.f) : (double)defn;
  double m = stats[f] / cnt;
  double v = stats[(Cmask + 1) + f] / cnt - m * m;
  float inv = rsqrtf((float)v + 1e-5f);
  float val = (h[i] - (float)m) * inv * g[f] + b[f];
  if (sc) val += sc[i];
  h[i] = val;
}

// pooling / coarse graph construction
__global__ void k_pool5(const float* __restrict__ h, const float* __restrict__ pos,
                        const int* __restrict__ batch, int* __restrict__ cl,
                        float* cnt, float* posps, float* xp) {
  int i = blockIdx.x * blockDim.x + threadIdx.x;
  if (i >= NN * 128) return;
  int node = i >> 7, f = i & 127;
  float px = pos[node*3+0], py = pos[node*3+1];
  int vx = min(max((int)floorf(px / 16.f), 0), 14);
  int vy = min(max((int)floorf(py / 12.f), 0), 14);
  int c = batch[node] * NV5 + vy * 15 + vx;
  if (f == 0) { cl[node] = c; atomicAdd(&cnt[c], 1.f); }
  if (f < 3) atomicAdd(&posps[c*3+f], pos[node*3+f]);
  atomicMaxF(&xp[(size_t)c * 128 + f], h[(size_t)node * 128 + f]);
}

__global__ void k_pool5_fin(float* xp, const float* __restrict__ cnt,
                            const float* __restrict__ posps, float* posp,
                            float* validf, float* nvalid) {
  int i = blockIdx.x * blockDim.x + threadIdx.x;
  if (i >= NCV * 128) return;
  int c = i >> 7, f = i & 127;
  bool val = cnt[c] > 0.f;
  if (f == 0) { validf[c] = val ? 1.f : 0.f; if (val) atomicAdd(nvalid, 1.f); }
  if (f < 3) posp[c*3+f] = posps[c*3+f] / fmaxf(cnt[c], 1.f);
  xp[i] = val ? xp[i] : 0.f;
}

__global__ void k_claim(const int* __restrict__ src, const int* __restrict__ tgt,
                        const int* __restrict__ cl, int* marker, int* ce_s, int* ce_d,
                        int* nedge, int* deg2, unsigned int* amax,
                        const float* __restrict__ posp) {
  int e = blockIdx.x * blockDim.x + threadIdx.x;
  if (e >= NE) return;
  int cs = cl[src[e]], ct = cl[tgt[e]];
  int key = cs * NCV + ct;
  if (atomicCAS(&marker[key], 0, 1) == 0 && cs != ct) {
    int id = atomicAdd(nedge, 1);
    ce_s[id] = cs; ce_d[id] = ct;
    atomicAdd(&deg2[ct], 1);
#pragma unroll
    for (int d = 0; d < 3; ++d) {
      float a = fabsf(posp[cs*3+d] - posp[ct*3+d]);
      atomicMax(amax, __float_as_uint(a));
    }
  }
}

__global__ void k_spline2(const int* __restrict__ ce_s, const int* __restrict__ ce_d,
                          const float* __restrict__ posp, const unsigned int* amaxp,
                          const int* nedgep, float* __restrict__ basis2,
                          int* __restrict__ widx2) {
  int i = blockIdx.x * blockDim.x + threadIdx.x;
  if (i >= *nedgep) return;
  float am = __uint_as_float(*amaxp);
  float den = 2.f * am + 1e-12f;
  int cs = ce_s[i], ct = ce_d[i];
  float p[3];
#pragma unroll
  for (int d = 0; d < 3; ++d) {
    float cart = posp[cs*3+d] - posp[ct*3+d];
    float ps = cart / den + 0.5f;
    ps = fminf(fmaxf(ps, 0.f), 1.f);
    p[d] = ps * 7.f;
  }
  float bas[8]; int idx[8];
  spline8(p[0], p[1], p[2], bas, idx);
#pragma unroll
  for (int s = 0; s < 8; ++s) { basis2[i*8+s] = bas[s]; widx2[i*8+s] = idx[s]; }
}

// histogram of pair spline-indices (to skip empty k bins in ygemm)
__global__ void k_phist(const int* __restrict__ widx2, const int* nedgep, int* pk_deg) {
  int i = blockIdx.x * blockDim.x + threadIdx.x;
  if (i >= 8 * (*nedgep)) return;
  atomicAdd(&pk_deg[widx2[i]], 1);
}

// batched Y[kk] = X(450x128) @ W[k0+kk](128x128); skips bins with no pairs.
__global__ __launch_bounds__(256)
void k_ygemm(const float* __restrict__ X, const float* __restrict__ Wk,
             float* __restrict__ Y, const int* __restrict__ pk_row, int k0) {
  int tile = blockIdx.x & 7;
  int kk = blockIdx.x >> 3;
  int k = k0 + kk;
  if (pk_row[k + 1] == pk_row[k]) return;
  int n0 = tile * 64;
  __shared__ float Xs[64][32];
  __shared__ float Ws[32][128];
  int tid = threadIdx.x;
  int tx = tid & 31;
  int ty = tid >> 5;
  float acc[8][4];
#pragma unroll
  for (int i = 0; i < 8; ++i)
#pragma unroll
    for (int j = 0; j < 4; ++j) acc[i][j] = 0.f;
  for (int c0 = 0; c0 < 128; c0 += 32) {
    for (int idx = tid; idx < 64 * 32; idx += 256) {
      int n = idx >> 5, c = idx & 31;
      int gn = n0 + n;
      Xs[n][c] = (gn < NCV) ? X[(size_t)gn * 128 + c0 + c] : 0.f;
    }
    for (int idx = tid; idx < 32 * 128; idx += 256) {
      int c = idx >> 7, f = idx & 127;
      Ws[c][f] = Wk[((size_t)k * 128 + c0 + c) * 128 + f];
    }
    __syncthreads();
#pragma unroll 8
    for (int c = 0; c < 32; ++c) {
      float4 wv = *(const float4*)&Ws[c][tx * 4];
#pragma unroll
      for (int i = 0; i < 8; ++i) {
        float xv = Xs[ty * 8 + i][c];
        acc[i][0] += xv * wv.x; acc[i][1] += xv * wv.y;
        acc[i][2] += xv * wv.z; acc[i][3] += xv * wv.w;
      }
    }
    __syncthreads();
  }
#pragma unroll
  for (int i = 0; i < 8; ++i) {
    int gn = n0 + ty * 8 + i;
    if (gn < NCV) {
      float4 v = make_float4(acc[i][0], acc[i][1], acc[i][2], acc[i][3]);
      *(float4*)&Y[((size_t)kk * NCV + gn) * 128 + tx * 4] = v;
    }
  }
}

// edge-parallel coarse messages: msg[e][f] (+)= sum_b basis*Y[k_b][src][f], k in [k0,k1)
__global__ __launch_bounds__(256)
void k_msg2(const float* __restrict__ Y, const int* __restrict__ ce_s,
            const float* __restrict__ basis2, const int* __restrict__ widx2,
            const int* nedgep, float* __restrict__ msg, int k0, int k1, int first) {
  int sub = threadIdx.x >> 7;
  int f = threadIdx.x & 127;
  int e = blockIdx.x * 2 + sub;
  if (e >= *nedgep) return;
  int s = ce_s[e];
  float acc = first ? 0.f : msg[(size_t)e * 128 + f];
#pragma unroll
  for (int b = 0; b < 8; ++b) {
    int k = widx2[e*8+b];
    if (k >= k0 && k < k1)
      acc += basis2[e*8+b] * Y[((size_t)(k - k0) * NCV + s) * 128 + f];
  }
  msg[(size_t)e * 128 + f] = acc;
}

__global__ void k_pool7(const float* __restrict__ h2, const float* __restrict__ posp,
                        const float* __restrict__ validf, float* x7, float* cnt7) {
  int i = blockIdx.x * blockDim.x + threadIdx.x;
  if (i >= NCV * 128) return;
  int c = i >> 7, f = i & 127;
  bool val = validf[c] > 0.f;
  float hv = val ? h2[i] : -1e30f;
  float px = posp[c*3+0], py = posp[c*3+1];
  int vx = min(max((int)floorf(px / 60.f), 0), 3);
  int vy = min(max((int)floorf(py / 45.f), 0), 3);
  int s = (c / NV5) * 16 + vy * 4 + vx;
  atomicMaxF(&x7[(size_t)s * 128 + f], hv);
  if (f == 0) atomicAdd(&cnt7[s], validf[c]);
}

__global__ void k_x7fin(float* x7, const float* __restrict__ cnt7) {
  int i = blockIdx.x * blockDim.x + threadIdx.x;
  if (i >= NSLOT * 128) return;
  x7[i] = (cnt7[i >> 7] > 0.f) ? x7[i] : 0.f;
}

__global__ void k_fc(const float* __restrict__ x7, const float* __restrict__ Wfc,
                     float* __restrict__ out) {
  int bid = blockIdx.x;
  int s = bid / NUM_OUT, o = bid % NUM_OUT;
  float p = 0.f;
  for (int j = threadIdx.x; j < 16 * 128; j += 256)
    p += x7[(size_t)s * 2048 + j] * Wfc[(size_t)o * 2048 + j];
  __shared__ float red[256];
  red[threadIdx.x] = p;
  __syncthreads();
  for (int st = 128; st > 0; st >>= 1) {
    if (threadIdx.x < st) red[threadIdx.x] += red[threadIdx.x + st];
    __syncthreads();
  }
  if (threadIdx.x == 0) out[s * NUM_OUT + o] = red[0];
}

} // namespace

extern "C" void kernel_launch(void* const* d_in, const int* in_sizes, int n_in,
                              void* d_out, int out_size, void* d_ws, size_t ws_size,
                              hipStream_t stream) {
  (void)in_sizes; (void)n_in; (void)out_size;
  const float* x_in  = (const float*)d_in[0];
  const float* pos   = (const float*)d_in[1];
  const float* eattr = (const float*)d_in[2];
  const int*   eidx  = (const int*)d_in[3];
  const int*   batch = (const int*)d_in[4];
  const float *Wl[8], *gl[8], *bl[8];
  for (int l = 1; l <= 7; ++l) {
    Wl[l] = (const float*)d_in[5 + (l - 1) * 3 + 0];
    gl[l] = (const float*)d_in[5 + (l - 1) * 3 + 1];
    bl[l] = (const float*)d_in[5 + (l - 1) * 3 + 2];
  }
  const float* Wfc = (const float*)d_in[26];
  float* out = (float*)d_out;

  const int* src = eidx;
  const int* tgt = eidx + NE;

  char* p = (char*)d_ws;
  auto alloc = [&](size_t bytes) -> void* {
    void* r = (void*)p;
    p += (bytes + 255) & ~(size_t)255;
    return r;
  };
  float* basis  = (float*)alloc((size_t)NE * 8 * 4);
  int*   widx   = (int*)  alloc((size_t)NE * 8 * 4);
  int*   deg    = (int*)  alloc((size_t)NN * 4);
  int*   row    = (int*)  alloc((size_t)(NN + 1) * 4);
  int*   cursor = (int*)  alloc((size_t)NN * 4);
  int*   perm   = (int*)  alloc((size_t)NE * 4);
  float* bufP   = (float*)alloc((size_t)NN * 128 * 4);
  float* bufQ   = (float*)alloc((size_t)NN * 128 * 4);
  float* bufR   = (float*)alloc((size_t)NN * 32 * 4);
  double* stats = (double*)alloc(256 * 8);
  int*   cl     = (int*)  alloc((size_t)NN * 4);
  float* cnt    = (float*)alloc((size_t)NCV * 4);
  float* posps  = (float*)alloc((size_t)NCV * 3 * 4);
  float* posp   = (float*)alloc((size_t)NCV * 3 * 4);
  float* validf = (float*)alloc((size_t)NCV * 4);
  float* xp     = (float*)alloc((size_t)NCV * 128 * 4);
  int*   marker = (int*)  alloc((size_t)NCV * NCV * 4);
  int*   nedge  = (int*)  alloc(256);
  unsigned int* amax = (unsigned int*)alloc(256);
  float* nvalid = (float*)alloc(256);
  int*   ce_s   = (int*)  alloc((size_t)NE * 4);
  int*   ce_d   = (int*)  alloc((size_t)NE * 4);
  float* basis2 = (float*)alloc((size_t)NE * 8 * 4);
  int*   widx2  = (int*)  alloc((size_t)NE * 8 * 4);
  int*   deg2   = (int*)  alloc((size_t)(NCV + 1) * 4);
  int*   row2   = (int*)  alloc((size_t)(NCV + 1) * 4);
  int*   cur2   = (int*)  alloc((size_t)NCV * 4);
  int*   perm2  = (int*)  alloc((size_t)NE * 4);
  int*   pk_deg = (int*)  alloc(513 * 4);
  int*   pk_row = (int*)  alloc(513 * 4);
  int*   pk_cur = (int*)  alloc(512 * 4);
  float* h2a    = (float*)alloc((size_t)NCV * 128 * 4);
  float* h2b    = (float*)alloc((size_t)NCV * 128 * 4);
  float* x7     = (float*)alloc((size_t)NSLOT * 128 * 4);
  float* cnt7   = (float*)alloc((size_t)NSLOT * 4);
  // packed bf16 weights (2 cin per uint)
  unsigned int* W2p = (unsigned int*)alloc((size_t)KT * 8 * 32 * 4);
  unsigned int* W3p = (unsigned int*)alloc((size_t)KT * 16 * 32 * 4);
  unsigned int* W4p = (unsigned int*)alloc((size_t)KT * 16 * 32 * 4);
  unsigned int* W5p = (unsigned int*)alloc((size_t)KT * 16 * 128 * 4);
  float* msg = (float*)alloc((size_t)NE * 128 * 4);

  // Y chunk: pick largest k-chunk that fits ws_size (constant across calls).
  size_t base = (size_t)(p - (char*)d_ws);
  int nk = 8;
  const int cands[] = {512, 256, 128, 64, 32, 16, 8};
  for (int c : cands) {
    if (base + (size_t)c * NCV * 128 * 4 <= ws_size) { nk = c; break; }
  }
  float* Y = (float*)alloc((size_t)nk * NCV * 128 * 4);

  // ---- init (ws is poisoned 0xAA before every call) ----
  hipMemsetAsync(deg, 0, (size_t)NN * 4, stream);
  hipMemsetAsync(cnt, 0, (size_t)NCV * 4, stream);
  hipMemsetAsync(posps, 0, (size_t)NCV * 3 * 4, stream);
  hipMemsetAsync(marker, 0, (size_t)NCV * NCV * 4, stream);
  hipMemsetAsync(nedge, 0, 4, stream);
  hipMemsetAsync(amax, 0, 4, stream);
  hipMemsetAsync(nvalid, 0, 4, stream);
  hipMemsetAsync(deg2, 0, (size_t)(NCV + 1) * 4, stream);
  hipMemsetAsync(cnt7, 0, (size_t)NSLOT * 4, stream);
  hipMemsetAsync(pk_deg, 0, 513 * 4, stream);
  k_fill<<<(NCV * 128 + 255) / 256, 256, 0, stream>>>(xp, -INFINITY, NCV * 128);
  k_fill<<<(NSLOT * 128 + 255) / 256, 256, 0, stream>>>(x7, -INFINITY, NSLOT * 128);

  // ---- weight packing ----
  k_wpack<16, 32><<<(KT * 8 * 32 + 255) / 256, 256, 0, stream>>>(Wl[2], W2p);
  k_wpack<32, 32><<<(KT * 16 * 32 + 255) / 256, 256, 0, stream>>>(Wl[3], W3p);
  k_wpack<32, 32><<<(KT * 16 * 32 + 255) / 256, 256, 0, stream>>>(Wl[4], W4p);
  k_wpack<32, 128><<<(KT * 16 * 128 + 255) / 256, 256, 0, stream>>>(Wl[5], W5p);

  // ---- fine graph prep ----
  k_spline<<<GE, 256, 0, stream>>>(eattr, basis, widx);
  k_hist<<<GE, 256, 0, stream>>>(tgt, deg, NE);
  k_scan<<<1, 256, 0, stream>>>(deg, row, cursor, NN);
  k_scatter<<<GE, 256, 0, stream>>>(tgt, cursor, perm, nullptr, NE);

  // ---- fine layers ----
  k_msg1<<<NE / 16, 256, 0, stream>>>(x_in, src, basis, widx, Wl[1], msg);
  k_agg<16><<<NN / 16, 256, 0, stream>>>(msg, perm, row, bufP, NN);
  hipMemsetAsync(stats, 0, 2 * 16 * 8, stream);
  k_bn_stats<16><<<64, 256, 0, stream>>>(bufP, nullptr, stats, NN);
  k_bn_norm<<<NN * 16 / 256, 256, 0, stream>>>(bufP, stats, nullptr, NN, gl[1], bl[1], nullptr, NN * 16, 15);

  k_msg_mid<16><<<NE / 8, 256, 0, stream>>>(bufP, src, basis, widx, W2p, msg);
  k_agg<32><<<NN / 8, 256, 0, stream>>>(msg, perm, row, bufQ, NN);
  hipMemsetAsync(stats, 0, 2 * 32 * 8, stream);
  k_bn_stats<32><<<64, 256, 0, stream>>>(bufQ, nullptr, stats, NN);
  k_bn_norm<<<NN * 32 / 256, 256, 0, stream>>>(bufQ, stats, nullptr, NN, gl[2], bl[2], nullptr, NN * 32, 31);

  k_msg_mid<32><<<NE / 8, 256, 0, stream>>>(bufQ, src, basis, widx, W3p, msg);
  k_agg<32><<<NN / 8, 256, 0, stream>>>(msg, perm, row, bufR, NN);
  hipMemsetAsync(stats, 0, 2 * 32 * 8, stream);
  k_bn_stats<32><<<64, 256, 0, stream>>>(bufR, nullptr, stats, NN);
  k_bn_norm<<<NN * 32 / 256, 256, 0, stream>>>(bufR, stats, nullptr, NN, gl[3], bl[3], nullptr, NN * 32, 31);

  k_msg_mid<32><<<NE / 8, 256, 0, stream>>>(bufR, src, basis, widx, W4p, msg);
  k_agg<32><<<NN / 8, 256, 0, stream>>>(msg, perm, row, bufP, NN);
  hipMemsetAsync(stats, 0, 2 * 32 * 8, stream);
  k_bn_stats<32><<<64, 256, 0, stream>>>(bufP, nullptr, stats, NN);
  k_bn_norm<<<NN * 32 / 256, 256, 0, stream>>>(bufP, stats, nullptr, NN, gl[4], bl[4], bufQ, NN * 32, 31);

  k_msg5<<<NE / 2, 256, 0, stream>>>(bufP, src, basis, widx, W5p, msg);
  k_agg<128><<<NN / 2, 256, 0, stream>>>(msg, perm, row, bufQ, NN);
  hipMemsetAsync(stats, 0, 2 * 128 * 8, stream);
  k_bn_stats<128><<<64, 256, 0, stream>>>(bufQ, nullptr, stats, NN);
  k_bn_norm<<<NN * 128 / 256, 256, 0, stream>>>(bufQ, stats, nullptr, NN, gl[5], bl[5], nullptr, NN * 128, 127);

  // ---- voxel max-pool ----
  k_pool5<<<NN * 128 / 256, 256, 0, stream>>>(bufQ, pos, batch, cl, cnt, posps, xp);
  k_pool5_fin<<<NCV * 128 / 256, 256, 0, stream>>>(xp, cnt, posps, posp, validf, nvalid);

  // ---- coarse edges ----
  k_claim<<<GE, 256, 0, stream>>>(src, tgt, cl, marker, ce_s, ce_d, nedge, deg2, amax, posp);
  k_spline2<<<GE, 256, 0, stream>>>(ce_s, ce_d, posp, amax, nedge, basis2, widx2);
  k_phist<<<GP, 256, 0, stream>>>(widx2, nedge, pk_deg);
  k_scan<<<1, 256, 0, stream>>>(deg2, row2, cur2, NCV);
  k_scatter<<<GE, 256, 0, stream>>>(ce_d, cur2, perm2, nedge, 0);
  k_scan<<<1, 256, 0, stream>>>(pk_deg, pk_row, pk_cur, 512);

  // ---- coarse layer 6: xp -> h2a ----
  for (int k0 = 0; k0 < KT; k0 += nk) {
    k_ygemm<<<8 * nk, 256, 0, stream>>>(xp, Wl[6], Y, pk_row, k0);
    k_msg2<<<NE / 2, 256, 0, stream>>>(Y, ce_s, basis2, widx2, nedge, msg, k0, k0 + nk, k0 == 0 ? 1 : 0);
  }
  k_agg<128><<<NCV / 2 + 1, 256, 0, stream>>>(msg, perm2, row2, h2a, NCV);
  hipMemsetAsync(stats, 0, 2 * 128 * 8, stream);
  k_bn_stats<128><<<64, 256, 0, stream>>>(h2a, validf, stats, NCV);
  k_bn_norm<<<NCV * 128 / 256, 256, 0, stream>>>(h2a, stats, nvalid, NCV, gl[6], bl[6], nullptr, NCV * 128, 127);

  // ---- coarse layer 7: h2a -> h2b, then += xp ----
  for (int k0 = 0; k0 < KT; k0 += nk) {
    k_ygemm<<<8 * nk, 256, 0, stream>>>(h2a, Wl[7], Y, pk_row, k0);
    k_msg2<<<NE / 2, 256, 0, stream>>>(Y, ce_s, basis2, widx2, nedge, msg, k0, k0 + nk, k0 == 0 ? 1 : 0);
  }
  k_agg<128><<<NCV / 2 + 1, 256, 0, stream>>>(msg, perm2, row2, h2b, NCV);
  hipMemsetAsync(stats, 0, 2 * 128 * 8, stream);
  k_bn_stats<128><<<64, 256, 0, stream>>>(h2b, validf, stats, NCV);
  k_bn_norm<<<NCV * 128 / 256, 256, 0, stream>>>(h2b, stats, nvalid, NCV, gl[7], bl[7], xp, NCV * 128, 127);

  // ---- final pool + FC ----
  k_pool7<<<NCV * 128 / 256, 256, 0, stream>>>(h2b, posp, validf, x7, cnt7);
  k_x7fin<<<NSLOT * 128 / 256, 256, 0, stream>>>(x7, cnt7);
  k_fc<<<NB * NUM_OUT, 256, 0, stream>>>(x7, Wfc, out);
}

// Round 11
// 951.679 us; speedup vs baseline: 1.7500x; 1.2070x over previous
//
#include <hip/hip_runtime.h>
#include <hip/hip_bf16.h>
#include <cstdint>
#include <cstddef>
#include <math.h>

// GraphResNet forward, round 11.
// Single change vs R10: k_phist now pre-aggregates in an LDS histogram
// (R10's direct global atomicAdd on skewed spline bins serialized ~300k
// L2 RMWs on a few cachelines -> 205us at 0.03% VALUBusy).

namespace {

constexpr int NB    = 2;
constexpr int NPER  = 4096;
constexpr int NN    = NB * NPER;        // 8192 nodes
constexpr int NE    = NN * 6;           // 49152 edges
constexpr int KT    = 512;              // 8^3 spline table
constexpr int NV5   = 225;
constexpr int NCV   = NB * NV5;         // 450 coarse voxels
constexpr int NSLOT = NB * 16;
constexpr int NUM_OUT = 11;
constexpr int GE    = (NE + 255) / 256;

__device__ __forceinline__ void atomicMaxF(float* a, float v) {
  if (v >= 0.f) atomicMax((int*)a, __float_as_int(v));
  else          atomicMin((unsigned int*)a, __float_as_uint(v));
}

__device__ __forceinline__ float bfLO(unsigned int u) { return __uint_as_float(u << 16); }
__device__ __forceinline__ float bfHI(unsigned int u) { return __uint_as_float(u & 0xffff0000u); }

__device__ __forceinline__ void spline8(float p0, float p1, float p2, float* bas, int* idx) {
  float l0 = floorf(p0), l1 = floorf(p1), l2 = floorf(p2);
  float f0 = p0 - l0, f1 = p1 - l1, f2 = p2 - l2;
  int i0 = (int)l0, i1 = (int)l1, i2 = (int)l2;
#pragma unroll
  for (int s = 0; s < 8; ++s) {
    int b0 = s & 1, b1 = (s >> 1) & 1, b2 = (s >> 2) & 1;
    float w = (b0 ? f0 : 1.f - f0) * (b1 ? f1 : 1.f - f1) * (b2 ? f2 : 1.f - f2);
    int j0 = min(max(i0 + b0, 0), 7);
    int j1 = min(max(i1 + b1, 0), 7);
    int j2 = min(max(i2 + b2, 0), 7);
    bas[s] = w;
    idx[s] = j0 + (j1 << 3) + (j2 << 6);
  }
}

__global__ void k_fill(float* p, float v, int n) {
  int i = blockIdx.x * blockDim.x + threadIdx.x;
  if (i < n) p[i] = v;
}

__global__ void k_spline(const float* __restrict__ ea, float* __restrict__ basis,
                         int* __restrict__ widx) {
  int e = blockIdx.x * blockDim.x + threadIdx.x;
  if (e >= NE) return;
  float bas[8]; int idx[8];
  spline8(ea[e*3+0]*7.f, ea[e*3+1]*7.f, ea[e*3+2]*7.f, bas, idx);
#pragma unroll
  for (int s = 0; s < 8; ++s) { basis[e*8+s] = bas[s]; widx[e*8+s] = idx[s]; }
}

__global__ void k_hist(const int* __restrict__ t, int* deg, int n) {
  int i = blockIdx.x * blockDim.x + threadIdx.x;
  if (i < n) atomicAdd(&deg[t[i]], 1);
}

__global__ void k_scan(const int* __restrict__ deg, int* __restrict__ row,
                       int* __restrict__ cursor, int n) {
  __shared__ int part[256];
  int tid = threadIdx.x;
  int chunk = (n + 255) / 256;
  int s0 = tid * chunk, s1 = min(s0 + chunk, n);
  int s = 0;
  for (int i = s0; i < s1; ++i) s += deg[i];
  part[tid] = s;
  __syncthreads();
  for (int off = 1; off < 256; off <<= 1) {
    int v = (tid >= off) ? part[tid - off] : 0;
    __syncthreads();
    part[tid] += v;
    __syncthreads();
  }
  int run = (tid == 0) ? 0 : part[tid - 1];
  for (int i = s0; i < s1; ++i) { row[i] = run; cursor[i] = run; run += deg[i]; }
  if (tid == 255) row[n] = run;
}

__global__ void k_scatter(const int* __restrict__ t, int* cursor, int* __restrict__ perm,
                          const int* nptr, int nconst) {
  int n = nptr ? *nptr : nconst;
  int i = blockIdx.x * blockDim.x + threadIdx.x;
  if (i >= n) return;
  int pos = atomicAdd(&cursor[t[i]], 1);
  perm[pos] = i;
}

// pack W[k][c][COUT] (f32) -> Wp[k][c/2][COUT] (two bf16 per uint: lo=c even, hi=c odd)
template<int CIN, int COUT>
__global__ void k_wpack(const float* __restrict__ W, unsigned int* __restrict__ Wp) {
  int i = blockIdx.x * 256 + threadIdx.x;
  if (i >= KT * (CIN / 2) * COUT) return;
  int k = i / ((CIN / 2) * COUT);
  int r = i % ((CIN / 2) * COUT);
  int c2 = r / COUT, f = r % COUT;
  float lo = W[((size_t)k * CIN + 2 * c2) * COUT + f];
  float hi = W[((size_t)k * CIN + 2 * c2 + 1) * COUT + f];
  union { __hip_bfloat16 b; unsigned short u; } cl, ch;
  cl.b = __float2bfloat16(lo); ch.b = __float2bfloat16(hi);
  Wp[i] = (unsigned int)cl.u | ((unsigned int)ch.u << 16);
}

// ---- edge-parallel fine-conv messages ----

__global__ __launch_bounds__(256)
void k_msg1(const float* __restrict__ x, const int* __restrict__ src,
            const float* __restrict__ basis, const int* __restrict__ widx,
            const float* __restrict__ W1, float* __restrict__ msg) {
  int e = blockIdx.x * 16 + (threadIdx.x >> 4);
  int f = threadIdx.x & 15;
  if (e >= NE) return;
  float xv = x[src[e]];
  float acc = 0.f;
#pragma unroll
  for (int b = 0; b < 8; ++b) {
    float bb = basis[e*8+b];
    int k = widx[e*8+b];
    acc += bb * W1[(size_t)k * 16 + f];
  }
  msg[(size_t)e * 16 + f] = acc * xv;
}

template<int CIN>
__global__ __launch_bounds__(256)
void k_msg_mid(const float* __restrict__ x, const int* __restrict__ src,
               const float* __restrict__ basis, const int* __restrict__ widx,
               const unsigned int* __restrict__ Wp, float* __restrict__ msg) {
  int e = blockIdx.x * 8 + (threadIdx.x >> 5);
  int f = threadIdx.x & 31;
  if (e >= NE) return;
  int s = src[e];
  float xv = (f < CIN) ? x[(size_t)s * CIN + f] : 0.f;
  float bs[8]; int ks[8];
#pragma unroll
  for (int b = 0; b < 8; ++b) { bs[b] = basis[e*8+b]; ks[b] = widx[e*8+b]; }
  float acc0 = 0.f, acc1 = 0.f;
#pragma unroll
  for (int b = 0; b < 8; ++b) {
    const unsigned int* P = Wp + (size_t)ks[b] * (CIN / 2 * 32) + f;
    float m0 = 0.f, m1 = 0.f;
#pragma unroll
    for (int c2 = 0; c2 < CIN / 2; ++c2) {
      unsigned int u = P[c2 * 32];
      m0 += __shfl(xv, 2 * c2, 32) * bfLO(u);
      m1 += __shfl(xv, 2 * c2 + 1, 32) * bfHI(u);
    }
    acc0 += bs[b] * m0; acc1 += bs[b] * m1;
  }
  msg[(size_t)e * 32 + f] = acc0 + acc1;
}

__global__ __launch_bounds__(256)
void k_msg5(const float* __restrict__ x, const int* __restrict__ src,
            const float* __restrict__ basis, const int* __restrict__ widx,
            const unsigned int* __restrict__ W5p, float* __restrict__ msg) {
  __shared__ float xs[2][32];
  int sub = threadIdx.x >> 7;
  int f = threadIdx.x & 127;
  int e = blockIdx.x * 2 + sub;
  int s = src[e];
  if (f < 32) xs[sub][f] = x[(size_t)s * 32 + f];
  __syncthreads();
  float xv[32];
#pragma unroll
  for (int c = 0; c < 32; ++c) xv[c] = xs[sub][c];
  float bs[8]; int ks[8];
#pragma unroll
  for (int b = 0; b < 8; ++b) { bs[b] = basis[e*8+b]; ks[b] = widx[e*8+b]; }
  float acc0 = 0.f, acc1 = 0.f;
#pragma unroll
  for (int b = 0; b < 8; ++b) {
    const unsigned int* P = W5p + (size_t)ks[b] * 2048 + f;
    float m0 = 0.f, m1 = 0.f;
#pragma unroll
    for (int c2 = 0; c2 < 16; ++c2) {
      unsigned int u = P[c2 * 128];
      m0 += xv[2 * c2] * bfLO(u);
      m1 += xv[2 * c2 + 1] * bfHI(u);
    }
    acc0 += bs[b] * m0; acc1 += bs[b] * m1;
  }
  msg[(size_t)e * 128 + f] = acc0 + acc1;
}

template<int C>
__global__ __launch_bounds__(256)
void k_agg(const float* __restrict__ msg, const int* __restrict__ perm,
           const int* __restrict__ row, float* __restrict__ hout, int n) {
  constexpr int TPB = 256 / C;
  int t = blockIdx.x * TPB + threadIdx.x / C;
  int f = threadIdx.x % C;
  if (t >= n) return;
  int r0 = row[t], r1 = row[t + 1];
  float acc = 0.f;
  for (int i = r0; i < r1; ++i) acc += msg[(size_t)perm[i] * C + f];
  float h = acc / (float)max(r1 - r0, 1);
  hout[(size_t)t * C + f] = h > 0.f ? h : expm1f(h);
}

// BN stats / norm
template<int C>
__global__ void k_bn_stats(const float* __restrict__ h, const float* __restrict__ maskf,
                           double* __restrict__ stats, int n) {
  constexpr int RPB = 256 / C;
  int f = threadIdx.x % C;
  int r = threadIdx.x / C;
  float s = 0.f, ss = 0.f;
  for (int i = blockIdx.x * RPB + r; i < n; i += gridDim.x * RPB) {
    float v = h[(size_t)i * C + f];
    if (maskf) v *= maskf[i];
    s += v; ss += v * v;
  }
  __shared__ float ls[256], lss[256];
  ls[threadIdx.x] = s; lss[threadIdx.x] = ss;
  __syncthreads();
  if (r == 0) {
#pragma unroll
    for (int j = 1; j < RPB; ++j) { s += ls[j * C + f]; ss += lss[j * C + f]; }
    atomicAdd(&stats[f], (double)s);
    atomicAdd(&stats[C + f], (double)ss);
  }
}

__global__ void k_bn_norm(float* __restrict__ h, const double* __restrict__ stats,
                          const float* cntp, int defn, const float* __restrict__ g,
                          const float* __restrict__ b, const float* __restrict__ sc,
                          int total, int Cmask) {
  int i = blockIdx.x * blockDim.x + threadIdx.x;
  if (i >= total) return;
  int f = i & Cmask;
  double cnt = cntp ? (double)fmaxf(*cntp, 1.f) : (double)defn;
  double m = stats[f] / cnt;
  double v = stats[(Cmask + 1) + f] / cnt - m * m;
  float inv = rsqrtf((float)v + 1e-5f);
  float val = (h[i] - (float)m) * inv * g[f] + b[f];
  if (sc) val += sc[i];
  h[i] = val;
}

// pooling / coarse graph construction
__global__ void k_pool5(const float* __restrict__ h, const float* __restrict__ pos,
                        const int* __restrict__ batch, int* __restrict__ cl,
                        float* cnt, float* posps, float* xp) {
  int i = blockIdx.x * blockDim.x + threadIdx.x;
  if (i >= NN * 128) return;
  int node = i >> 7, f = i & 127;
  float px = pos[node*3+0], py = pos[node*3+1];
  int vx = min(max((int)floorf(px / 16.f), 0), 14);
  int vy = min(max((int)floorf(py / 12.f), 0), 14);
  int c = batch[node] * NV5 + vy * 15 + vx;
  if (f == 0) { cl[node] = c; atomicAdd(&cnt[c], 1.f); }
  if (f < 3) atomicAdd(&posps[c*3+f], pos[node*3+f]);
  atomicMaxF(&xp[(size_t)c * 128 + f], h[(size_t)node * 128 + f]);
}

__global__ void k_pool5_fin(float* xp, const float* __restrict__ cnt,
                            const float* __restrict__ posps, float* posp,
                            float* validf, float* nvalid) {
  int i = blockIdx.x * blockDim.x + threadIdx.x;
  if (i >= NCV * 128) return;
  int c = i >> 7, f = i & 127;
  bool val = cnt[c] > 0.f;
  if (f == 0) { validf[c] = val ? 1.f : 0.f; if (val) atomicAdd(nvalid, 1.f); }
  if (f < 3) posp[c*3+f] = posps[c*3+f] / fmaxf(cnt[c], 1.f);
  xp[i] = val ? xp[i] : 0.f;
}

__global__ void k_claim(const int* __restrict__ src, const int* __restrict__ tgt,
                        const int* __restrict__ cl, int* marker, int* ce_s, int* ce_d,
                        int* nedge, int* deg2, unsigned int* amax,
                        const float* __restrict__ posp) {
  int e = blockIdx.x * blockDim.x + threadIdx.x;
  if (e >= NE) return;
  int cs = cl[src[e]], ct = cl[tgt[e]];
  int key = cs * NCV + ct;
  if (atomicCAS(&marker[key], 0, 1) == 0 && cs != ct) {
    int id = atomicAdd(nedge, 1);
    ce_s[id] = cs; ce_d[id] = ct;
    atomicAdd(&deg2[ct], 1);
#pragma unroll
    for (int d = 0; d < 3; ++d) {
      float a = fabsf(posp[cs*3+d] - posp[ct*3+d]);
      atomicMax(amax, __float_as_uint(a));
    }
  }
}

__global__ void k_spline2(const int* __restrict__ ce_s, const int* __restrict__ ce_d,
                          const float* __restrict__ posp, const unsigned int* amaxp,
                          const int* nedgep, float* __restrict__ basis2,
                          int* __restrict__ widx2) {
  int i = blockIdx.x * blockDim.x + threadIdx.x;
  if (i >= *nedgep) return;
  float am = __uint_as_float(*amaxp);
  float den = 2.f * am + 1e-12f;
  int cs = ce_s[i], ct = ce_d[i];
  float p[3];
#pragma unroll
  for (int d = 0; d < 3; ++d) {
    float cart = posp[cs*3+d] - posp[ct*3+d];
    float ps = cart / den + 0.5f;
    ps = fminf(fmaxf(ps, 0.f), 1.f);
    p[d] = ps * 7.f;
  }
  float bas[8]; int idx[8];
  spline8(p[0], p[1], p[2], bas, idx);
#pragma unroll
  for (int s = 0; s < 8; ++s) { basis2[i*8+s] = bas[s]; widx2[i*8+s] = idx[s]; }
}

// histogram of pair spline-indices with LDS pre-aggregation (skewed bins!)
__global__ __launch_bounds__(256)
void k_phist(const int* __restrict__ widx2, const int* nedgep, int* pk_deg) {
  __shared__ int h[KT];
  for (int i = threadIdx.x; i < KT; i += 256) h[i] = 0;
  __syncthreads();
  int n = 8 * (*nedgep);
  for (int i = blockIdx.x * 256 + threadIdx.x; i < n; i += gridDim.x * 256)
    atomicAdd(&h[widx2[i]], 1);
  __syncthreads();
  for (int i = threadIdx.x; i < KT; i += 256) {
    int v = h[i];
    if (v) atomicAdd(&pk_deg[i], v);
  }
}

// batched Y[kk] = X(450x128) @ W[k0+kk](128x128); skips bins with no pairs.
__global__ __launch_bounds__(256)
void k_ygemm(const float* __restrict__ X, const float* __restrict__ Wk,
             float* __restrict__ Y, const int* __restrict__ pk_row, int k0) {
  int tile = blockIdx.x & 7;
  int kk = blockIdx.x >> 3;
  int k = k0 + kk;
  if (pk_row[k + 1] == pk_row[k]) return;
  int n0 = tile * 64;
  __shared__ float Xs[64][32];
  __shared__ float Ws[32][128];
  int tid = threadIdx.x;
  int tx = tid & 31;
  int ty = tid >> 5;
  float acc[8][4];
#pragma unroll
  for (int i = 0; i < 8; ++i)
#pragma unroll
    for (int j = 0; j < 4; ++j) acc[i][j] = 0.f;
  for (int c0 = 0; c0 < 128; c0 += 32) {
    for (int idx = tid; idx < 64 * 32; idx += 256) {
      int n = idx >> 5, c = idx & 31;
      int gn = n0 + n;
      Xs[n][c] = (gn < NCV) ? X[(size_t)gn * 128 + c0 + c] : 0.f;
    }
    for (int idx = tid; idx < 32 * 128; idx += 256) {
      int c = idx >> 7, f = idx & 127;
      Ws[c][f] = Wk[((size_t)k * 128 + c0 + c) * 128 + f];
    }
    __syncthreads();
#pragma unroll 8
    for (int c = 0; c < 32; ++c) {
      float4 wv = *(const float4*)&Ws[c][tx * 4];
#pragma unroll
      for (int i = 0; i < 8; ++i) {
        float xv = Xs[ty * 8 + i][c];
        acc[i][0] += xv * wv.x; acc[i][1] += xv * wv.y;
        acc[i][2] += xv * wv.z; acc[i][3] += xv * wv.w;
      }
    }
    __syncthreads();
  }
#pragma unroll
  for (int i = 0; i < 8; ++i) {
    int gn = n0 + ty * 8 + i;
    if (gn < NCV) {
      float4 v = make_float4(acc[i][0], acc[i][1], acc[i][2], acc[i][3]);
      *(float4*)&Y[((size_t)kk * NCV + gn) * 128 + tx * 4] = v;
    }
  }
}

// edge-parallel coarse messages: msg[e][f] (+)= sum_b basis*Y[k_b][src][f], k in [k0,k1)
__global__ __launch_bounds__(256)
void k_msg2(const float* __restrict__ Y, const int* __restrict__ ce_s,
            const float* __restrict__ basis2, const int* __restrict__ widx2,
            const int* nedgep, float* __restrict__ msg, int k0, int k1, int first) {
  int sub = threadIdx.x >> 7;
  int f = threadIdx.x & 127;
  int e = blockIdx.x * 2 + sub;
  if (e >= *nedgep) return;
  int s = ce_s[e];
  float acc = first ? 0.f : msg[(size_t)e * 128 + f];
#pragma unroll
  for (int b = 0; b < 8; ++b) {
    int k = widx2[e*8+b];
    if (k >= k0 && k < k1)
      acc += basis2[e*8+b] * Y[((size_t)(k - k0) * NCV + s) * 128 + f];
  }
  msg[(size_t)e * 128 + f] = acc;
}

__global__ void k_pool7(const float* __restrict__ h2, const float* __restrict__ posp,
                        const float* __restrict__ validf, float* x7, float* cnt7) {
  int i = blockIdx.x * blockDim.x + threadIdx.x;
  if (i >= NCV * 128) return;
  int c = i >> 7, f = i & 127;
  bool val = validf[c] > 0.f;
  float hv = val ? h2[i] : -1e30f;
  float px = posp[c*3+0], py = posp[c*3+1];
  int vx = min(max((int)floorf(px / 60.f), 0), 3);
  int vy = min(max((int)floorf(py / 45.f), 0), 3);
  int s = (c / NV5) * 16 + vy * 4 + vx;
  atomicMaxF(&x7[(size_t)s * 128 + f], hv);
  if (f == 0) atomicAdd(&cnt7[s], validf[c]);
}

__global__ void k_x7fin(float* x7, const float* __restrict__ cnt7) {
  int i = blockIdx.x * blockDim.x + threadIdx.x;
  if (i >= NSLOT * 128) return;
  x7[i] = (cnt7[i >> 7] > 0.f) ? x7[i] : 0.f;
}

__global__ void k_fc(const float* __restrict__ x7, const float* __restrict__ Wfc,
                     float* __restrict__ out) {
  int bid = blockIdx.x;
  int s = bid / NUM_OUT, o = bid % NUM_OUT;
  float p = 0.f;
  for (int j = threadIdx.x; j < 16 * 128; j += 256)
    p += x7[(size_t)s * 2048 + j] * Wfc[(size_t)o * 2048 + j];
  __shared__ float red[256];
  red[threadIdx.x] = p;
  __syncthreads();
  for (int st = 128; st > 0; st >>= 1) {
    if (threadIdx.x < st) red[threadIdx.x] += red[threadIdx.x + st];
    __syncthreads();
  }
  if (threadIdx.x == 0) out[s * NUM_OUT + o] = red[0];
}

} // namespace

extern "C" void kernel_launch(void* const* d_in, const int* in_sizes, int n_in,
                              void* d_out, int out_size, void* d_ws, size_t ws_size,
                              hipStream_t stream) {
  (void)in_sizes; (void)n_in; (void)out_size;
  const float* x_in  = (const float*)d_in[0];
  const float* pos   = (const float*)d_in[1];
  const float* eattr = (const float*)d_in[2];
  const int*   eidx  = (const int*)d_in[3];
  const int*   batch = (const int*)d_in[4];
  const float *Wl[8], *gl[8], *bl[8];
  for (int l = 1; l <= 7; ++l) {
    Wl[l] = (const float*)d_in[5 + (l - 1) * 3 + 0];
    gl[l] = (const float*)d_in[5 + (l - 1) * 3 + 1];
    bl[l] = (const float*)d_in[5 + (l - 1) * 3 + 2];
  }
  const float* Wfc = (const float*)d_in[26];
  float* out = (float*)d_out;

  const int* src = eidx;
  const int* tgt = eidx + NE;

  char* p = (char*)d_ws;
  auto alloc = [&](size_t bytes) -> void* {
    void* r = (void*)p;
    p += (bytes + 255) & ~(size_t)255;
    return r;
  };
  float* basis  = (float*)alloc((size_t)NE * 8 * 4);
  int*   widx   = (int*)  alloc((size_t)NE * 8 * 4);
  int*   deg    = (int*)  alloc((size_t)NN * 4);
  int*   row    = (int*)  alloc((size_t)(NN + 1) * 4);
  int*   cursor = (int*)  alloc((size_t)NN * 4);
  int*   perm   = (int*)  alloc((size_t)NE * 4);
  float* bufP   = (float*)alloc((size_t)NN * 128 * 4);
  float* bufQ   = (float*)alloc((size_t)NN * 128 * 4);
  float* bufR   = (float*)alloc((size_t)NN * 32 * 4);
  double* stats = (double*)alloc(256 * 8);
  int*   cl     = (int*)  alloc((size_t)NN * 4);
  float* cnt    = (float*)alloc((size_t)NCV * 4);
  float* posps  = (float*)alloc((size_t)NCV * 3 * 4);
  float* posp   = (float*)alloc((size_t)NCV * 3 * 4);
  float* validf = (float*)alloc((size_t)NCV * 4);
  float* xp     = (float*)alloc((size_t)NCV * 128 * 4);
  int*   marker = (int*)  alloc((size_t)NCV * NCV * 4);
  int*   nedge  = (int*)  alloc(256);
  unsigned int* amax = (unsigned int*)alloc(256);
  float* nvalid = (float*)alloc(256);
  int*   ce_s   = (int*)  alloc((size_t)NE * 4);
  int*   ce_d   = (int*)  alloc((size_t)NE * 4);
  float* basis2 = (float*)alloc((size_t)NE * 8 * 4);
  int*   widx2  = (int*)  alloc((size_t)NE * 8 * 4);
  int*   deg2   = (int*)  alloc((size_t)(NCV + 1) * 4);
  int*   row2   = (int*)  alloc((size_t)(NCV + 1) * 4);
  int*   cur2   = (int*)  alloc((size_t)NCV * 4);
  int*   perm2  = (int*)  alloc((size_t)NE * 4);
  int*   pk_deg = (int*)  alloc(513 * 4);
  int*   pk_row = (int*)  alloc(513 * 4);
  int*   pk_cur = (int*)  alloc(512 * 4);
  float* h2a    = (float*)alloc((size_t)NCV * 128 * 4);
  float* h2b    = (float*)alloc((size_t)NCV * 128 * 4);
  float* x7     = (float*)alloc((size_t)NSLOT * 128 * 4);
  float* cnt7   = (float*)alloc((size_t)NSLOT * 4);
  // packed bf16 weights (2 cin per uint)
  unsigned int* W2p = (unsigned int*)alloc((size_t)KT * 8 * 32 * 4);
  unsigned int* W3p = (unsigned int*)alloc((size_t)KT * 16 * 32 * 4);
  unsigned int* W4p = (unsigned int*)alloc((size_t)KT * 16 * 32 * 4);
  unsigned int* W5p = (unsigned int*)alloc((size_t)KT * 16 * 128 * 4);
  float* msg = (float*)alloc((size_t)NE * 128 * 4);

  // Y chunk: pick largest k-chunk that fits ws_size (constant across calls).
  size_t base = (size_t)(p - (char*)d_ws);
  int nk = 8;
  const int cands[] = {512, 256, 128, 64, 32, 16, 8};
  for (int c : cands) {
    if (base + (size_t)c * NCV * 128 * 4 <= ws_size) { nk = c; break; }
  }
  float* Y = (float*)alloc((size_t)nk * NCV * 128 * 4);

  // ---- init (ws is poisoned 0xAA before every call) ----
  hipMemsetAsync(deg, 0, (size_t)NN * 4, stream);
  hipMemsetAsync(cnt, 0, (size_t)NCV * 4, stream);
  hipMemsetAsync(posps, 0, (size_t)NCV * 3 * 4, stream);
  hipMemsetAsync(marker, 0, (size_t)NCV * NCV * 4, stream);
  hipMemsetAsync(nedge, 0, 4, stream);
  hipMemsetAsync(amax, 0, 4, stream);
  hipMemsetAsync(nvalid, 0, 4, stream);
  hipMemsetAsync(deg2, 0, (size_t)(NCV + 1) * 4, stream);
  hipMemsetAsync(cnt7, 0, (size_t)NSLOT * 4, stream);
  hipMemsetAsync(pk_deg, 0, 513 * 4, stream);
  k_fill<<<(NCV * 128 + 255) / 256, 256, 0, stream>>>(xp, -INFINITY, NCV * 128);
  k_fill<<<(NSLOT * 128 + 255) / 256, 256, 0, stream>>>(x7, -INFINITY, NSLOT * 128);

  // ---- weight packing ----
  k_wpack<16, 32><<<(KT * 8 * 32 + 255) / 256, 256, 0, stream>>>(Wl[2], W2p);
  k_wpack<32, 32><<<(KT * 16 * 32 + 255) / 256, 256, 0, stream>>>(Wl[3], W3p);
  k_wpack<32, 32><<<(KT * 16 * 32 + 255) / 256, 256, 0, stream>>>(Wl[4], W4p);
  k_wpack<32, 128><<<(KT * 16 * 128 + 255) / 256, 256, 0, stream>>>(Wl[5], W5p);

  // ---- fine graph prep ----
  k_spline<<<GE, 256, 0, stream>>>(eattr, basis, widx);
  k_hist<<<GE, 256, 0, stream>>>(tgt, deg, NE);
  k_scan<<<1, 256, 0, stream>>>(deg, row, cursor, NN);
  k_scatter<<<GE, 256, 0, stream>>>(tgt, cursor, perm, nullptr, NE);

  // ---- fine layers ----
  k_msg1<<<NE / 16, 256, 0, stream>>>(x_in, src, basis, widx, Wl[1], msg);
  k_agg<16><<<NN / 16, 256, 0, stream>>>(msg, perm, row, bufP, NN);
  hipMemsetAsync(stats, 0, 2 * 16 * 8, stream);
  k_bn_stats<16><<<64, 256, 0, stream>>>(bufP, nullptr, stats, NN);
  k_bn_norm<<<NN * 16 / 256, 256, 0, stream>>>(bufP, stats, nullptr, NN, gl[1], bl[1], nullptr, NN * 16, 15);

  k_msg_mid<16><<<NE / 8, 256, 0, stream>>>(bufP, src, basis, widx, W2p, msg);
  k_agg<32><<<NN / 8, 256, 0, stream>>>(msg, perm, row, bufQ, NN);
  hipMemsetAsync(stats, 0, 2 * 32 * 8, stream);
  k_bn_stats<32><<<64, 256, 0, stream>>>(bufQ, nullptr, stats, NN);
  k_bn_norm<<<NN * 32 / 256, 256, 0, stream>>>(bufQ, stats, nullptr, NN, gl[2], bl[2], nullptr, NN * 32, 31);

  k_msg_mid<32><<<NE / 8, 256, 0, stream>>>(bufQ, src, basis, widx, W3p, msg);
  k_agg<32><<<NN / 8, 256, 0, stream>>>(msg, perm, row, bufR, NN);
  hipMemsetAsync(stats, 0, 2 * 32 * 8, stream);
  k_bn_stats<32><<<64, 256, 0, stream>>>(bufR, nullptr, stats, NN);
  k_bn_norm<<<NN * 32 / 256, 256, 0, stream>>>(bufR, stats, nullptr, NN, gl[3], bl[3], nullptr, NN * 32, 31);

  k_msg_mid<32><<<NE / 8, 256, 0, stream>>>(bufR, src, basis, widx, W4p, msg);
  k_agg<32><<<NN / 8, 256, 0, stream>>>(msg, perm, row, bufP, NN);
  hipMemsetAsync(stats, 0, 2 * 32 * 8, stream);
  k_bn_stats<32><<<64, 256, 0, stream>>>(bufP, nullptr, stats, NN);
  k_bn_norm<<<NN * 32 / 256, 256, 0, stream>>>(bufP, stats, nullptr, NN, gl[4], bl[4], bufQ, NN * 32, 31);

  k_msg5<<<NE / 2, 256, 0, stream>>>(bufP, src, basis, widx, W5p, msg);
  k_agg<128><<<NN / 2, 256, 0, stream>>>(msg, perm, row, bufQ, NN);
  hipMemsetAsync(stats, 0, 2 * 128 * 8, stream);
  k_bn_stats<128><<<64, 256, 0, stream>>>(bufQ, nullptr, stats, NN);
  k_bn_norm<<<NN * 128 / 256, 256, 0, stream>>>(bufQ, stats, nullptr, NN, gl[5], bl[5], nullptr, NN * 128, 127);

  // ---- voxel max-pool ----
  k_pool5<<<NN * 128 / 256, 256, 0, stream>>>(bufQ, pos, batch, cl, cnt, posps, xp);
  k_pool5_fin<<<NCV * 128 / 256, 256, 0, stream>>>(xp, cnt, posps, posp, validf, nvalid);

  // ---- coarse edges ----
  k_claim<<<GE, 256, 0, stream>>>(src, tgt, cl, marker, ce_s, ce_d, nedge, deg2, amax, posp);
  k_spline2<<<GE, 256, 0, stream>>>(ce_s, ce_d, posp, amax, nedge, basis2, widx2);
  k_phist<<<128, 256, 0, stream>>>(widx2, nedge, pk_deg);
  k_scan<<<1, 256, 0, stream>>>(deg2, row2, cur2, NCV);
  k_scatter<<<GE, 256, 0, stream>>>(ce_d, cur2, perm2, nedge, 0);
  k_scan<<<1, 256, 0, stream>>>(pk_deg, pk_row, pk_cur, 512);

  // ---- coarse layer 6: xp -> h2a ----
  for (int k0 = 0; k0 < KT; k0 += nk) {
    k_ygemm<<<8 * nk, 256, 0, stream>>>(xp, Wl[6], Y, pk_row, k0);
    k_msg2<<<NE / 2, 256, 0, stream>>>(Y, ce_s, basis2, widx2, nedge, msg, k0, k0 + nk, k0 == 0 ? 1 : 0);
  }
  k_agg<128><<<NCV / 2 + 1, 256, 0, stream>>>(msg, perm2, row2, h2a, NCV);
  hipMemsetAsync(stats, 0, 2 * 128 * 8, stream);
  k_bn_stats<128><<<64, 256, 0, stream>>>(h2a, validf, stats, NCV);
  k_bn_norm<<<NCV * 128 / 256, 256, 0, stream>>>(h2a, stats, nvalid, NCV, gl[6], bl[6], nullptr, NCV * 128, 127);

  // ---- coarse layer 7: h2a -> h2b, then += xp ----
  for (int k0 = 0; k0 < KT; k0 += nk) {
    k_ygemm<<<8 * nk, 256, 0, stream>>>(h2a, Wl[7], Y, pk_row, k0);
    k_msg2<<<NE / 2, 256, 0, stream>>>(Y, ce_s, basis2, widx2, nedge, msg, k0, k0 + nk, k0 == 0 ? 1 : 0);
  }
  k_agg<128><<<NCV / 2 + 1, 256, 0, stream>>>(msg, perm2, row2, h2b, NCV);
  hipMemsetAsync(stats, 0, 2 * 128 * 8, stream);
  k_bn_stats<128><<<64, 256, 0, stream>>>(h2b, validf, stats, NCV);
  k_bn_norm<<<NCV * 128 / 256, 256, 0, stream>>>(h2b, stats, nvalid, NCV, gl[7], bl[7], xp, NCV * 128, 127);

  // ---- final pool + FC ----
  k_pool7<<<NCV * 128 / 256, 256, 0, stream>>>(h2b, posp, validf, x7, cnt7);
  k_x7fin<<<NSLOT * 128 / 256, 256, 0, stream>>>(x7, cnt7);
  k_fc<<<NB * NUM_OUT, 256, 0, stream>>>(x7, Wfc, out);
}